// Round 12
// baseline (464.347 us; speedup 1.0000x reference)
//
#include <hip/hip_runtime.h>
#include <hip/hip_bf16.h>
#include <hip/hip_fp16.h>

#define TABN   4096
#define ROWS   (TABN + 1)           // table rows per interaction
#define DMAX   6.5f
#define DELTA  (DMAX / (float)TABN)
#define INVD   ((float)TABN / DMAX)
#define LOG2F_ 0.6931471805599453f
#define SBITS  9                    // 512 tgt-nodes per bucket
#define TILE   2048                 // edges per stage tile

__device__ __forceinline__ float ssp(float x) {
    // shifted softplus via fast-math intrinsics: log(1+e^x) - log(2)
    return fmaxf(x, 0.f) + __logf(1.f + __expf(-fabsf(x))) - LOG2F_;
}

// ---------------- filter lookup table: W_i(d) for d = t*DELTA ----------------
__global__ void ftab_kernel(const float* __restrict__ fw1, const float* __restrict__ fb1,
                            const float* __restrict__ fw2, const float* __restrict__ fb2,
                            float* __restrict__ ftab) {
    int t = blockIdx.x;          // 0..ROWS-1
    int i = blockIdx.y;          // interaction 0/1
    int j = threadIdx.x;         // 0..63 channel
    float d = (float)t * DELTA;
    float acc = fb1[i * 64 + j];
    for (int k = 0; k < 51; ++k) {
        float u = d - 0.1f * (float)k;
        float r = __expf(-10.f * u * u);
        acc = fmaf(r, fw1[((size_t)i * 51 + k) * 64 + j], acc);
    }
    __shared__ float h[64];
    h[j] = ssp(acc);
    __syncthreads();
    float o = fb2[i * 64 + j];
    for (int k = 0; k < 64; ++k)
        o = fmaf(h[k], fw2[((size_t)i * 64 + k) * 64 + j], o);
    ftab[((size_t)i * ROWS + t) * 64 + j] = o;
}

// ------- pack lerp endpoints as fp16 pair: 4B/entry, 1MB/interaction --------
__global__ void fpack_kernel(const float* __restrict__ ftab, __half2* __restrict__ fpair) {
    int t = blockIdx.x, i = blockIdx.y, j = threadIdx.x;
    const float* r = ftab + ((size_t)i * ROWS + t) * 64;
    fpair[((size_t)i * TABN + t) * 64 + j] = __floats2half2_rn(r[j], r[j + 64]);
}

// ---------------- bucket histogram (LDS-privatized) ----------------
__global__ void bhist_kernel(const int* __restrict__ ei, int* __restrict__ bcnt, int E) {
    __shared__ int h[256];
    int tid = threadIdx.x;
    h[tid] = 0;
    __syncthreads();
    for (int e = blockIdx.x * blockDim.x + tid; e < E; e += gridDim.x * blockDim.x)
        atomicAdd(&h[ei[E + e] >> SBITS], 1);
    __syncthreads();
    if (h[tid]) atomicAdd(&bcnt[tid], h[tid]);
}

// ---------------- bucket exclusive scan (parallel, one block) ----------------
// R11 lesson: the single-thread loop was ~200 serial dependent global loads.
__global__ void bscan_kernel(const int* __restrict__ bcnt, int* __restrict__ bbase,
                             int* __restrict__ bcur, int nbuck) {
    __shared__ int sm[256];
    int tid = threadIdx.x;
    int v = (tid < nbuck) ? bcnt[tid] : 0;
    sm[tid] = v;
    __syncthreads();
    for (int o = 1; o < 256; o <<= 1) {
        int t = (tid >= o) ? sm[tid - o] : 0;
        __syncthreads();
        sm[tid] += t;
        __syncthreads();
    }
    if (tid < nbuck) { bbase[tid] = sm[tid] - v; bcur[tid] = sm[tid] - v; }
    if (tid == 255) bbase[nbuck] = sm[255];
}

// ------- stage: LDS multisplit of edge tiles into bucket-ordered stg ---------
// payload: w0 = src | (t&511)<<17 ; w1 = ti<<20 | frac_q20
__global__ __launch_bounds__(256, 4)
void stage_kernel(const float* __restrict__ pos, const int* __restrict__ ei,
                  int* __restrict__ bcur, int2* __restrict__ stg, int E, int nbuck) {
    __shared__ int hist[256], loff[256], gbase[256], sc[256];
    __shared__ int2 sp[TILE];
    __shared__ short sb[TILE];
    int tid = threadIdx.x;
    int tile0 = blockIdx.x * TILE;
    int cnt = min(TILE, E - tile0);
    hist[tid] = 0;
    __syncthreads();
    int myrank[8], myb[8]; int2 mypay[8];
#pragma unroll
    for (int u = 0; u < 8; ++u) {
        int i = u * 256 + tid;
        myb[u] = -1;
        if (i < cnt) {
            int e = tile0 + i;
            int s = ei[e], t = ei[E + e];
            float dx = pos[3 * s]     - pos[3 * t];
            float dy = pos[3 * s + 1] - pos[3 * t + 1];
            float dz = pos[3 * s + 2] - pos[3 * t + 2];
            float d = sqrtf(dx * dx + dy * dy + dz * dz);
            float ds = fminf(d, DMAX) * INVD;
            int ti = min((int)ds, TABN - 1);
            int frq = min((int)((ds - (float)ti) * 1048576.f), 1048575);
            mypay[u] = make_int2(s | ((t & 511) << 17), (ti << 20) | frq);
            myb[u] = t >> SBITS;
            myrank[u] = atomicAdd(&hist[myb[u]], 1);
        }
    }
    __syncthreads();
    sc[tid] = hist[tid];
    __syncthreads();
    for (int o = 1; o < 256; o <<= 1) {
        int v = (tid >= o) ? sc[tid - o] : 0;
        __syncthreads();
        sc[tid] += v;
        __syncthreads();
    }
    loff[tid] = sc[tid] - hist[tid];
    if (tid < nbuck && hist[tid] > 0) gbase[tid] = atomicAdd(&bcur[tid], hist[tid]);
    __syncthreads();
#pragma unroll
    for (int u = 0; u < 8; ++u)
        if (myb[u] >= 0) {
            int idx = loff[myb[u]] + myrank[u];
            sp[idx] = mypay[u];
            sb[idx] = (short)myb[u];
        }
    __syncthreads();
    for (int i = tid; i < cnt; i += 256) {
        int b = sb[i];
        stg[gbase[b] + (i - loff[b])] = sp[i];
    }
}

// ------- place: per bucket, exact CSR placement with LDS-only atomics --------
__global__ __launch_bounds__(256)
void place_kernel(const int2* __restrict__ stg, const int* __restrict__ bbase,
                  int* __restrict__ off, int2* __restrict__ edata, int n, int nbuck) {
    int b = blockIdx.x;
    int n0 = b << SBITS;
    int nn = min(512, n - n0);
    int q0 = bbase[b], q1 = bbase[b + 1];
    __shared__ int cnt[512], cur[512], sc[256];
    int tid = threadIdx.x;
    cnt[tid] = 0; cnt[tid + 256] = 0;
    __syncthreads();
    for (int q = q0 + tid; q < q1; q += 256)
        atomicAdd(&cnt[(stg[q].x >> 17) & 511], 1);
    __syncthreads();
    int c0 = cnt[2 * tid], c1 = cnt[2 * tid + 1];
    int s = c0 + c1;
    sc[tid] = s;
    __syncthreads();
    for (int o = 1; o < 256; o <<= 1) {
        int v = (tid >= o) ? sc[tid - o] : 0;
        __syncthreads();
        sc[tid] += v;
        __syncthreads();
    }
    int run = sc[tid] - s;        // exclusive over node pairs
    cur[2 * tid] = run;
    cur[2 * tid + 1] = run + c0;
    if (2 * tid < nn)     off[n0 + 2 * tid]     = q0 + run;
    if (2 * tid + 1 < nn) off[n0 + 2 * tid + 1] = q0 + run + c0;
    if (b == nbuck - 1 && tid == 0) off[n] = q1;
    __syncthreads();
    for (int q = q0 + tid; q < q1; q += 256) {
        int2 v = stg[q];
        int p = atomicAdd(&cur[(v.x >> 17) & 511], 1);
        edata[q0 + p] = v;
    }
}

// ---------------- x = emb_z[z] ----------------
__global__ void embed_kernel(const int* __restrict__ z, const float* __restrict__ emb,
                             float* __restrict__ x, int n) {
    int idx = blockIdx.x * blockDim.x + threadIdx.x;   // over n*16 float4 chunks
    if (idx >= n * 16) return;
    int node = idx >> 4, c = idx & 15;
    ((float4*)x)[idx] = ((const float4*)emb)[z[node] * 16 + c];
}

// ---------------- solvent head for the 4 unique solvent rows ----------------
__global__ void solv_kernel(const float* __restrict__ emb_solv,
                            const float* __restrict__ w1, const float* __restrict__ b1,
                            const float* __restrict__ w2, const float* __restrict__ b2,
                            float* __restrict__ s4) {
    __shared__ float h[4][64];
    int t = threadIdx.x, r = t >> 6, j = t & 63;
    float acc = b1[j];
    for (int k = 0; k < 64; ++k) acc = fmaf(emb_solv[r * 64 + k], w1[k * 64 + j], acc);
    h[r][j] = ssp(acc);
    __syncthreads();
    if (j < 32) {
        float a = b2[j];
        for (int k = 0; k < 64; ++k) a = fmaf(h[r][k], w2[k * 32 + j], a);
        s4[r * 32 + j] = a;
    }
}

// ------------- m = x@W+b, fp16 output (interaction 0 only) -------------------
__global__ __launch_bounds__(256, 4)
void mm1h_kernel(const float* __restrict__ in, const float* __restrict__ w,
                 const float* __restrict__ b, __half* __restrict__ out, int n) {
    int tid = threadIdx.x;
    int q = __builtin_amdgcn_readfirstlane(tid >> 6);   // 0..3, wave-uniform
    int node = blockIdx.x * 64 + (tid & 63);
    node = min(node, n - 1);                    // no divergent return
    const float4* in4 = (const float4*)(in + (size_t)node * 64);
    const float* wq = w + q * 16;
    const float* bq = b + q * 16;
    float acc[16];
#pragma unroll
    for (int j = 0; j < 16; ++j) acc[j] = bq[j];
#pragma unroll 2
    for (int kk = 0; kk < 16; ++kk) {
        float4 xv = in4[kk];
        const float* w0 = wq + kk * 256;
#pragma unroll
        for (int j = 0; j < 16; ++j) acc[j] = fmaf(xv.x, w0[j],       acc[j]);
#pragma unroll
        for (int j = 0; j < 16; ++j) acc[j] = fmaf(xv.y, w0[64 + j],  acc[j]);
#pragma unroll
        for (int j = 0; j < 16; ++j) acc[j] = fmaf(xv.z, w0[128 + j], acc[j]);
#pragma unroll
        for (int j = 0; j < 16; ++j) acc[j] = fmaf(xv.w, w0[192 + j], acc[j]);
    }
    __half2* o2 = (__half2*)(out + (size_t)node * 64 + q * 16);
#pragma unroll
    for (int c = 0; c < 8; ++c)
        o2[c] = __floats2half2_rn(acc[2 * c], acc[2 * c + 1]);
}

// ===== fused interaction: agg -> ssp-MLP -> residual (-> next m) =============
// block = 64 nodes, 4 waves. Phase A: wave-per-node aggregation into LDS
// (stride-65 rows, conflict-free). Phase B: quarter-split 2-layer MLP from
// LDS + residual -> x. Phase C (EMIT_M): next interaction's m = x @ lw + lb
// from the output rows staged back into LDS. Saves the agg round-trip
// (2x25.6MB), one x re-read, and 3 launches vs the unfused chain.
template <bool EMIT_M>
__global__ __launch_bounds__(256, 4)
void fused_kernel(const int* __restrict__ off, const int2* __restrict__ edata,
                  const __half* __restrict__ m, const __half2* __restrict__ fpair,
                  const float* __restrict__ w1, const float* __restrict__ b1,
                  const float* __restrict__ w2, const float* __restrict__ b2,
                  float* __restrict__ x,
                  const float* __restrict__ lw, const float* __restrict__ lb,
                  __half* __restrict__ mout, int n) {
    __shared__ float agg_l[64 * 65];
    __shared__ float h2[64 * 65];
    int tid = threadIdx.x;
    int wid = tid >> 6, lane = tid & 63;
    int base = blockIdx.x * 64;
    const float FRS = 1.f / 1048576.f;

    // ---- phase A: each wave aggregates 16 nodes ----
    for (int i = 0; i < 16; ++i) {
        int ln = wid * 16 + i;
        int node = min(base + ln, n - 1);
        int e0 = __builtin_amdgcn_readfirstlane(off[node]);
        int e1 = __builtin_amdgcn_readfirstlane(off[node + 1]);
        float acc0 = 0.f, acc1 = 0.f, acc2 = 0.f, acc3 = 0.f;
        int e = e0;
        for (; e + 4 <= e1; e += 4) {
            float mv[4], wv[4];
#pragma unroll
            for (int u = 0; u < 4; ++u) {
                int2 pd = edata[e + u];
                int px = __builtin_amdgcn_readfirstlane(pd.x);
                int py = __builtin_amdgcn_readfirstlane(pd.y);
                int s = px & 0x1FFFF;
                unsigned ti = ((unsigned)py) >> 20;
                float fr = (float)(py & 0xFFFFF) * FRS;
                mv[u] = __half2float(m[(size_t)s * 64 + lane]);
                float2 wf = __half22float2(fpair[(size_t)ti * 64 + lane]);
                wv[u] = fmaf(fr, wf.y - wf.x, wf.x);
            }
            acc0 = fmaf(mv[0], wv[0], acc0);
            acc1 = fmaf(mv[1], wv[1], acc1);
            acc2 = fmaf(mv[2], wv[2], acc2);
            acc3 = fmaf(mv[3], wv[3], acc3);
        }
        for (; e < e1; ++e) {
            int2 pd = edata[e];
            int px = __builtin_amdgcn_readfirstlane(pd.x);
            int py = __builtin_amdgcn_readfirstlane(pd.y);
            int s = px & 0x1FFFF;
            unsigned ti = ((unsigned)py) >> 20;
            float fr = (float)(py & 0xFFFFF) * FRS;
            float mm = __half2float(m[(size_t)s * 64 + lane]);
            float2 wf = __half22float2(fpair[(size_t)ti * 64 + lane]);
            acc0 = fmaf(mm, fmaf(fr, wf.y - wf.x, wf.x), acc0);
        }
        agg_l[ln * 65 + lane] = (acc0 + acc1) + (acc2 + acc3);
    }
    __syncthreads();

    // ---- phase B1: h = ssp(agg @ W1 + b1), quarter split ----
    int q = __builtin_amdgcn_readfirstlane(wid);
    int nl = lane;
    int node = min(base + nl, n - 1);
    const float* w1q = w1 + q * 16;
    float acc[16];
#pragma unroll
    for (int j = 0; j < 16; ++j) acc[j] = b1[q * 16 + j];
#pragma unroll 4
    for (int k = 0; k < 64; ++k) {
        float hk = agg_l[nl * 65 + k];
        const float* w0 = w1q + k * 64;
#pragma unroll
        for (int j = 0; j < 16; ++j) acc[j] = fmaf(hk, w0[j], acc[j]);
    }
#pragma unroll
    for (int j = 0; j < 16; ++j) h2[nl * 65 + q * 16 + j] = ssp(acc[j]);
    __syncthreads();

    // ---- phase B2: out = h @ W2 + b2 + res -> x (and LDS for phase C) ----
    const float* w2q = w2 + q * 16;
    float acc2[16];
#pragma unroll
    for (int j = 0; j < 16; ++j) acc2[j] = b2[q * 16 + j];
#pragma unroll 4
    for (int k = 0; k < 64; ++k) {
        float hk = h2[nl * 65 + k];
        const float* w0 = w2q + k * 64;
#pragma unroll
        for (int j = 0; j < 16; ++j) acc2[j] = fmaf(hk, w0[j], acc2[j]);
    }
    const float4* r4 = (const float4*)(x + (size_t)node * 64 + q * 16);
    float4* o4 = (float4*)(x + (size_t)node * 64 + q * 16);
#pragma unroll
    for (int c = 0; c < 4; ++c) {
        float4 v;
        v.x = acc2[4 * c];     v.y = acc2[4 * c + 1];
        v.z = acc2[4 * c + 2]; v.w = acc2[4 * c + 3];
        float4 rv = r4[c];
        v.x += rv.x; v.y += rv.y; v.z += rv.z; v.w += rv.w;
        o4[c] = v;
        if constexpr (EMIT_M) {
            agg_l[nl * 65 + q * 16 + 4 * c]     = v.x;
            agg_l[nl * 65 + q * 16 + 4 * c + 1] = v.y;
            agg_l[nl * 65 + q * 16 + 4 * c + 2] = v.z;
            agg_l[nl * 65 + q * 16 + 4 * c + 3] = v.w;
        }
    }
    if constexpr (EMIT_M) {
        __syncthreads();
        // ---- phase C: next m = x @ lw + lb (fp16 out) ----
        const float* lwq = lw + q * 16;
        float accm[16];
#pragma unroll
        for (int j = 0; j < 16; ++j) accm[j] = lb[q * 16 + j];
#pragma unroll 4
        for (int k = 0; k < 64; ++k) {
            float hk = agg_l[nl * 65 + k];
            const float* w0 = lwq + k * 64;
#pragma unroll
            for (int j = 0; j < 16; ++j) accm[j] = fmaf(hk, w0[j], accm[j]);
        }
        __half2* o2 = (__half2*)(mout + (size_t)node * 64 + q * 16);
#pragma unroll
        for (int c = 0; c < 8; ++c)
            o2[c] = __floats2half2_rn(accm[2 * c], accm[2 * c + 1]);
    }
}

// ------- fused 2-layer: out = ssp(in@W1+b1)@W2+b2, quarter split (post) ------
#define HSTR 65
__global__ __launch_bounds__(256, 4)
void mm2_kernel(const float* __restrict__ in,
                const float* __restrict__ w1, const float* __restrict__ b1,
                const float* __restrict__ w2, const float* __restrict__ b2,
                float* __restrict__ out, int n) {
    __shared__ float hl[64 * HSTR];
    int tid = threadIdx.x;
    int q = __builtin_amdgcn_readfirstlane(tid >> 6);   // 0..3, wave-uniform
    int nl = tid & 63;
    int node = blockIdx.x * 64 + nl;
    node = min(node, n - 1);

    const float4* in4 = (const float4*)(in + (size_t)node * 64);
    const float* w1q = w1 + q * 16;
    const float* b1q = b1 + q * 16;
    float acc[16];
#pragma unroll
    for (int j = 0; j < 16; ++j) acc[j] = b1q[j];
#pragma unroll 2
    for (int kk = 0; kk < 16; ++kk) {
        float4 xv = in4[kk];
        const float* w0 = w1q + kk * 256;
#pragma unroll
        for (int j = 0; j < 16; ++j) acc[j] = fmaf(xv.x, w0[j],       acc[j]);
#pragma unroll
        for (int j = 0; j < 16; ++j) acc[j] = fmaf(xv.y, w0[64 + j],  acc[j]);
#pragma unroll
        for (int j = 0; j < 16; ++j) acc[j] = fmaf(xv.z, w0[128 + j], acc[j]);
#pragma unroll
        for (int j = 0; j < 16; ++j) acc[j] = fmaf(xv.w, w0[192 + j], acc[j]);
    }
    float* hrow = hl + nl * HSTR + q * 16;
#pragma unroll
    for (int j = 0; j < 16; ++j) hrow[j] = ssp(acc[j]);
    __syncthreads();

    const float* hfull = hl + nl * HSTR;
    const float* w2q = w2 + q * 16;
    const float* b2q = b2 + q * 16;
    float acc2[16];
#pragma unroll
    for (int j = 0; j < 16; ++j) acc2[j] = b2q[j];
#pragma unroll 4
    for (int k = 0; k < 64; ++k) {
        float hk = hfull[k];
        const float* w0 = w2q + k * 64;
#pragma unroll
        for (int j = 0; j < 16; ++j) acc2[j] = fmaf(hk, w0[j], acc2[j]);
    }
    float4* o4 = (float4*)(out + (size_t)node * 64 + q * 16);
#pragma unroll
    for (int c = 0; c < 4; ++c) {
        float4 v;
        v.x = acc2[4 * c];     v.y = acc2[4 * c + 1];
        v.z = acc2[4 * c + 2]; v.w = acc2[4 * c + 3];
        o4[c] = v;
    }
}

// ---------------- scatter-mean pooling via binary search (batch sorted) -----
__global__ void pool_kernel(const float* __restrict__ h, const int* __restrict__ batch,
                            float* __restrict__ pooled, int n_nodes) {
    int g = blockIdx.x, j = threadIdx.x;   // block = 64
    int lo = 0, hi = n_nodes;
    while (lo < hi) { int mid = (lo + hi) >> 1; if (batch[mid] < g) lo = mid + 1; else hi = mid; }
    int start = lo;
    int lo2 = start, hi2 = n_nodes;
    while (lo2 < hi2) { int mid = (lo2 + hi2) >> 1; if (batch[mid] < g + 1) lo2 = mid + 1; else hi2 = mid; }
    int end = lo2;
    float acc = 0.f;
    for (int r = start; r < end; ++r) acc += h[(size_t)r * 64 + j];
    float cnt = (float)(end - start);
    pooled[(size_t)g * 64 + j] = acc / fmaxf(cnt, 1.f);
}

// ---------------- final graph head: 96 -> 128 -> 32 -> 1 --------------------
__global__ void post2_kernel(const float* __restrict__ pooled, const float* __restrict__ s4,
                             const int* __restrict__ solvent,
                             const float* __restrict__ w1, const float* __restrict__ b1,
                             const float* __restrict__ w2, const float* __restrict__ b2,
                             const float* __restrict__ w3, const float* __restrict__ b3,
                             float* __restrict__ out) {
    __shared__ float in96[96];
    __shared__ float l1[128];
    __shared__ float l2[32];
    int g = blockIdx.x, t = threadIdx.x;   // block = 128
    if (t < 64)      in96[t] = pooled[(size_t)g * 64 + t];
    else if (t < 96) in96[t] = s4[solvent[g] * 32 + (t - 64)];
    __syncthreads();
    float acc = b1[t];
    for (int k = 0; k < 96; ++k) acc = fmaf(in96[k], w1[k * 128 + t], acc);
    l1[t] = ssp(acc);
    __syncthreads();
    if (t < 32) {
        float a = b2[t];
        for (int k = 0; k < 128; ++k) a = fmaf(l1[k], w2[k * 32 + t], a);
        l2[t] = ssp(a);
    }
    __syncthreads();
    if (t < 32) {
        float p = l2[t] * w3[t];
        for (int o = 16; o >= 1; o >>= 1) p += __shfl_down(p, o);
        if (t == 0) out[g] = p + b3[0];
    }
}

extern "C" void kernel_launch(void* const* d_in, const int* in_sizes, int n_in,
                              void* d_out, int out_size, void* d_ws, size_t ws_size,
                              hipStream_t stream) {
    const float* pos      = (const float*)d_in[0];
    const int*   ei       = (const int*)d_in[1];
    const int*   z        = (const int*)d_in[2];
    const int*   batch    = (const int*)d_in[3];
    const int*   solvent  = (const int*)d_in[4];
    const float* emb_z    = (const float*)d_in[5];
    const float* emb_solv = (const float*)d_in[6];
    const float* solv_w1  = (const float*)d_in[7];  const float* solv_b1 = (const float*)d_in[8];
    const float* solv_w2  = (const float*)d_in[9];  const float* solv_b2 = (const float*)d_in[10];
    const float* lin1_w   = (const float*)d_in[11]; const float* lin1_b  = (const float*)d_in[12];
    const float* mlp_w1   = (const float*)d_in[13]; const float* mlp_b1  = (const float*)d_in[14];
    const float* mlp_w2   = (const float*)d_in[15]; const float* mlp_b2  = (const float*)d_in[16];
    const float* filt_w1  = (const float*)d_in[17]; const float* filt_b1 = (const float*)d_in[18];
    const float* filt_w2  = (const float*)d_in[19]; const float* filt_b2 = (const float*)d_in[20];
    const float* post_w1  = (const float*)d_in[21]; const float* post_b1 = (const float*)d_in[22];
    const float* post_w2  = (const float*)d_in[23]; const float* post_b2 = (const float*)d_in[24];
    const float* p2w1 = (const float*)d_in[25]; const float* p2b1 = (const float*)d_in[26];
    const float* p2w2 = (const float*)d_in[27]; const float* p2b2 = (const float*)d_in[28];
    const float* p2w3 = (const float*)d_in[29]; const float* p2b3 = (const float*)d_in[30];
    float* out = (float*)d_out;

    const int N = in_sizes[2];
    const int E = in_sizes[1] / 2;
    const int G = in_sizes[4];
    const int NBUCK = (N + (1 << SBITS) - 1) >> SBITS;

    char* wp = (char*)d_ws;
    auto alloc = [&](size_t bytes) -> void* {
        void* r = (void*)wp;
        wp += (bytes + 255) & ~(size_t)255;
        return r;
    };
    int2*    stg    = (int2*)   alloc((size_t)E * 8);
    int2*    edata  = (int2*)   alloc((size_t)E * 8);
    int*     bcnt   = (int*)    alloc(256 * 4);
    int*     bbase  = (int*)    alloc(257 * 4);
    int*     bcur   = (int*)    alloc(256 * 4);
    int*     off    = (int*)    alloc((size_t)(N + 1) * 4);
    float*   ftab   = (float*)  alloc((size_t)2 * ROWS * 64 * 4);
    __half2* fpair  = (__half2*)alloc((size_t)2 * TABN * 64 * 4);
    float*   s4     = (float*)  alloc(4 * 32 * 4);
    float*   x      = (float*)  alloc((size_t)N * 64 * 4);
    __half*  m_h    = (__half*) alloc((size_t)N * 64 * 2);
    __half*  m_h2   = (__half*) alloc((size_t)N * 64 * 2);
    float*   hbuf   = (float*)  alloc((size_t)N * 64 * 4);
    float*   pooled = (float*)  alloc((size_t)G * 64 * 4);
    (void)ws_size; (void)n_in; (void)out_size;

    hipMemsetAsync(bcnt, 0, 256 * 4, stream);

    ftab_kernel<<<dim3(ROWS, 2), 64, 0, stream>>>(filt_w1, filt_b1, filt_w2, filt_b2, ftab);
    fpack_kernel<<<dim3(TABN, 2), 64, 0, stream>>>(ftab, fpair);
    bhist_kernel<<<512, 256, 0, stream>>>(ei, bcnt, E);
    bscan_kernel<<<1, 256, 0, stream>>>(bcnt, bbase, bcur, NBUCK);
    stage_kernel<<<(E + TILE - 1) / TILE, 256, 0, stream>>>(pos, ei, bcur, stg, E, NBUCK);
    place_kernel<<<NBUCK, 256, 0, stream>>>(stg, bbase, off, edata, N, NBUCK);
    embed_kernel<<<((size_t)N * 16 + 255) / 256, 256, 0, stream>>>(z, emb_z, x, N);
    solv_kernel<<<1, 256, 0, stream>>>(emb_solv, solv_w1, solv_b1, solv_w2, solv_b2, s4);

    int mmg = (N + 63) / 64;
    // interaction 0: m from embed output, then fused agg+MLP (+ m for inter 1)
    mm1h_kernel<<<mmg, 256, 0, stream>>>(x, lin1_w, lin1_b, m_h, N);
    fused_kernel<true><<<mmg, 256, 0, stream>>>(off, edata, m_h, fpair,
                                                mlp_w1, mlp_b1, mlp_w2, mlp_b2, x,
                                                lin1_w + 4096, lin1_b + 64, m_h2, N);
    // interaction 1
    fused_kernel<false><<<mmg, 256, 0, stream>>>(off, edata, m_h2, fpair + (size_t)TABN * 64,
                                                 mlp_w1 + 4096, mlp_b1 + 64,
                                                 mlp_w2 + 4096, mlp_b2 + 64, x,
                                                 nullptr, nullptr, nullptr, N);
    // post MLP: h = ssp(x@pw1+b1)@pw2+b2
    mm2_kernel<<<mmg, 256, 0, stream>>>(x, post_w1, post_b1, post_w2, post_b2, hbuf, N);

    pool_kernel<<<G, 64, 0, stream>>>(hbuf, batch, pooled, N);
    post2_kernel<<<G, 128, 0, stream>>>(pooled, s4, solvent, p2w1, p2b1, p2w2, p2b2,
                                        p2w3, p2b3, out);
}

// Round 13
// 372.125 us; speedup vs baseline: 1.2478x; 1.2478x over previous
//
#include <hip/hip_runtime.h>
#include <hip/hip_bf16.h>
#include <hip/hip_fp16.h>

#define TABN   4096
#define ROWS   (TABN + 1)           // table rows per interaction
#define DMAX   6.5f
#define DELTA  (DMAX / (float)TABN)
#define INVD   ((float)TABN / DMAX)
#define LOG2F_ 0.6931471805599453f
#define SBITS  9                    // 512 tgt-nodes per bucket
#define TILE   2048                 // edges per stage tile

__device__ __forceinline__ float ssp(float x) {
    // shifted softplus via fast-math intrinsics: log(1+e^x) - log(2)
    return fmaxf(x, 0.f) + __logf(1.f + __expf(-fabsf(x))) - LOG2F_;
}

// ---------------- filter lookup table: W_i(d) for d = t*DELTA ----------------
__global__ void ftab_kernel(const float* __restrict__ fw1, const float* __restrict__ fb1,
                            const float* __restrict__ fw2, const float* __restrict__ fb2,
                            float* __restrict__ ftab) {
    int t = blockIdx.x;          // 0..ROWS-1
    int i = blockIdx.y;          // interaction 0/1
    int j = threadIdx.x;         // 0..63 channel
    float d = (float)t * DELTA;
    float acc = fb1[i * 64 + j];
    for (int k = 0; k < 51; ++k) {
        float u = d - 0.1f * (float)k;
        float r = __expf(-10.f * u * u);
        acc = fmaf(r, fw1[((size_t)i * 51 + k) * 64 + j], acc);
    }
    __shared__ float h[64];
    h[j] = ssp(acc);
    __syncthreads();
    float o = fb2[i * 64 + j];
    for (int k = 0; k < 64; ++k)
        o = fmaf(h[k], fw2[((size_t)i * 64 + k) * 64 + j], o);
    ftab[((size_t)i * ROWS + t) * 64 + j] = o;
}

// ------- pack lerp endpoints as fp16 pair: 4B/entry, 1MB/interaction --------
__global__ void fpack_kernel(const float* __restrict__ ftab, __half2* __restrict__ fpair) {
    int t = blockIdx.x, i = blockIdx.y, j = threadIdx.x;
    const float* r = ftab + ((size_t)i * ROWS + t) * 64;
    fpair[((size_t)i * TABN + t) * 64 + j] = __floats2half2_rn(r[j], r[j + 64]);
}

// ---------------- bucket histogram (LDS-privatized) ----------------
__global__ void bhist_kernel(const int* __restrict__ ei, int* __restrict__ bcnt, int E) {
    __shared__ int h[256];
    int tid = threadIdx.x;
    h[tid] = 0;
    __syncthreads();
    for (int e = blockIdx.x * blockDim.x + tid; e < E; e += gridDim.x * blockDim.x)
        atomicAdd(&h[ei[E + e] >> SBITS], 1);
    __syncthreads();
    if (h[tid]) atomicAdd(&bcnt[tid], h[tid]);
}

// ---------------- bucket exclusive scan (parallel, one block) ----------------
__global__ void bscan_kernel(const int* __restrict__ bcnt, int* __restrict__ bbase,
                             int* __restrict__ bcur, int nbuck) {
    __shared__ int sm[256];
    int tid = threadIdx.x;
    int v = (tid < nbuck) ? bcnt[tid] : 0;
    sm[tid] = v;
    __syncthreads();
    for (int o = 1; o < 256; o <<= 1) {
        int t = (tid >= o) ? sm[tid - o] : 0;
        __syncthreads();
        sm[tid] += t;
        __syncthreads();
    }
    if (tid < nbuck) { bbase[tid] = sm[tid] - v; bcur[tid] = sm[tid] - v; }
    if (tid == 255) bbase[nbuck] = sm[255];
}

// ------- stage: LDS multisplit of edge tiles into bucket-ordered stg ---------
// payload: w0 = src | (t&511)<<17 ; w1 = ti<<20 | frac_q20
__global__ __launch_bounds__(256, 4)
void stage_kernel(const float* __restrict__ pos, const int* __restrict__ ei,
                  int* __restrict__ bcur, int2* __restrict__ stg, int E, int nbuck) {
    __shared__ int hist[256], loff[256], gbase[256], sc[256];
    __shared__ int2 sp[TILE];
    __shared__ short sb[TILE];
    int tid = threadIdx.x;
    int tile0 = blockIdx.x * TILE;
    int cnt = min(TILE, E - tile0);
    hist[tid] = 0;
    __syncthreads();
    int myrank[8], myb[8]; int2 mypay[8];
#pragma unroll
    for (int u = 0; u < 8; ++u) {
        int i = u * 256 + tid;
        myb[u] = -1;
        if (i < cnt) {
            int e = tile0 + i;
            int s = ei[e], t = ei[E + e];
            float dx = pos[3 * s]     - pos[3 * t];
            float dy = pos[3 * s + 1] - pos[3 * t + 1];
            float dz = pos[3 * s + 2] - pos[3 * t + 2];
            float d = sqrtf(dx * dx + dy * dy + dz * dz);
            float ds = fminf(d, DMAX) * INVD;
            int ti = min((int)ds, TABN - 1);
            int frq = min((int)((ds - (float)ti) * 1048576.f), 1048575);
            mypay[u] = make_int2(s | ((t & 511) << 17), (ti << 20) | frq);
            myb[u] = t >> SBITS;
            myrank[u] = atomicAdd(&hist[myb[u]], 1);
        }
    }
    __syncthreads();
    sc[tid] = hist[tid];
    __syncthreads();
    for (int o = 1; o < 256; o <<= 1) {
        int v = (tid >= o) ? sc[tid - o] : 0;
        __syncthreads();
        sc[tid] += v;
        __syncthreads();
    }
    loff[tid] = sc[tid] - hist[tid];
    if (tid < nbuck && hist[tid] > 0) gbase[tid] = atomicAdd(&bcur[tid], hist[tid]);
    __syncthreads();
#pragma unroll
    for (int u = 0; u < 8; ++u)
        if (myb[u] >= 0) {
            int idx = loff[myb[u]] + myrank[u];
            sp[idx] = mypay[u];
            sb[idx] = (short)myb[u];
        }
    __syncthreads();
    for (int i = tid; i < cnt; i += 256) {
        int b = sb[i];
        stg[gbase[b] + (i - loff[b])] = sp[i];
    }
}

// ------- place: per bucket, exact CSR placement with LDS-only atomics --------
__global__ __launch_bounds__(256)
void place_kernel(const int2* __restrict__ stg, const int* __restrict__ bbase,
                  int* __restrict__ off, int2* __restrict__ edata, int n, int nbuck) {
    int b = blockIdx.x;
    int n0 = b << SBITS;
    int nn = min(512, n - n0);
    int q0 = bbase[b], q1 = bbase[b + 1];
    __shared__ int cnt[512], cur[512], sc[256];
    int tid = threadIdx.x;
    cnt[tid] = 0; cnt[tid + 256] = 0;
    __syncthreads();
    for (int q = q0 + tid; q < q1; q += 256)
        atomicAdd(&cnt[(stg[q].x >> 17) & 511], 1);
    __syncthreads();
    int c0 = cnt[2 * tid], c1 = cnt[2 * tid + 1];
    int s = c0 + c1;
    sc[tid] = s;
    __syncthreads();
    for (int o = 1; o < 256; o <<= 1) {
        int v = (tid >= o) ? sc[tid - o] : 0;
        __syncthreads();
        sc[tid] += v;
        __syncthreads();
    }
    int run = sc[tid] - s;        // exclusive over node pairs
    cur[2 * tid] = run;
    cur[2 * tid + 1] = run + c0;
    if (2 * tid < nn)     off[n0 + 2 * tid]     = q0 + run;
    if (2 * tid + 1 < nn) off[n0 + 2 * tid + 1] = q0 + run + c0;
    if (b == nbuck - 1 && tid == 0) off[n] = q1;
    __syncthreads();
    for (int q = q0 + tid; q < q1; q += 256) {
        int2 v = stg[q];
        int p = atomicAdd(&cur[(v.x >> 17) & 511], 1);
        edata[q0 + p] = v;
    }
}

// ---------------- x = emb_z[z] ----------------
__global__ void embed_kernel(const int* __restrict__ z, const float* __restrict__ emb,
                             float* __restrict__ x, int n) {
    int idx = blockIdx.x * blockDim.x + threadIdx.x;   // over n*16 float4 chunks
    if (idx >= n * 16) return;
    int node = idx >> 4, c = idx & 15;
    ((float4*)x)[idx] = ((const float4*)emb)[z[node] * 16 + c];
}

// ---------------- solvent head for the 4 unique solvent rows ----------------
__global__ void solv_kernel(const float* __restrict__ emb_solv,
                            const float* __restrict__ w1, const float* __restrict__ b1,
                            const float* __restrict__ w2, const float* __restrict__ b2,
                            float* __restrict__ s4) {
    __shared__ float h[4][64];
    int t = threadIdx.x, r = t >> 6, j = t & 63;
    float acc = b1[j];
    for (int k = 0; k < 64; ++k) acc = fmaf(emb_solv[r * 64 + k], w1[k * 64 + j], acc);
    h[r][j] = ssp(acc);
    __syncthreads();
    if (j < 32) {
        float a = b2[j];
        for (int k = 0; k < 64; ++k) a = fmaf(h[r][k], w2[k * 32 + j], a);
        s4[r * 32 + j] = a;
    }
}

// ------------- m = x@W+b, fp16 output (interaction 0 only) -------------------
__global__ __launch_bounds__(256, 4)
void mm1h_kernel(const float* __restrict__ in, const float* __restrict__ w,
                 const float* __restrict__ b, __half* __restrict__ out, int n) {
    int tid = threadIdx.x;
    int q = __builtin_amdgcn_readfirstlane(tid >> 6);   // 0..3, wave-uniform
    int node = blockIdx.x * 64 + (tid & 63);
    node = min(node, n - 1);                    // no divergent return
    const float4* in4 = (const float4*)(in + (size_t)node * 64);
    const float* wq = w + q * 16;
    const float* bq = b + q * 16;
    float acc[16];
#pragma unroll
    for (int j = 0; j < 16; ++j) acc[j] = bq[j];
#pragma unroll 2
    for (int kk = 0; kk < 16; ++kk) {
        float4 xv = in4[kk];
        const float* w0 = wq + kk * 256;
#pragma unroll
        for (int j = 0; j < 16; ++j) acc[j] = fmaf(xv.x, w0[j],       acc[j]);
#pragma unroll
        for (int j = 0; j < 16; ++j) acc[j] = fmaf(xv.y, w0[64 + j],  acc[j]);
#pragma unroll
        for (int j = 0; j < 16; ++j) acc[j] = fmaf(xv.z, w0[128 + j], acc[j]);
#pragma unroll
        for (int j = 0; j < 16; ++j) acc[j] = fmaf(xv.w, w0[192 + j], acc[j]);
    }
    __half2* o2 = (__half2*)(out + (size_t)node * 64 + q * 16);
#pragma unroll
    for (int c = 0; c < 8; ++c)
        o2[c] = __floats2half2_rn(acc[2 * c], acc[2 * c + 1]);
}

// ---------------- per-node aggregation: agg[t] = sum_e m[src]*W(d) ----------
// wave per tgt node (100k waves of TLP — R12 lesson: never shrink this),
// lane = channel; edata words readfirstlane'd -> decode on SALU, m-gather
// saddr-form; m fp16 rows, fpair __half2 L2-resident table.
__global__ void agg_kernel(const int* __restrict__ off, const int2* __restrict__ edata,
                           const __half* __restrict__ m, const __half2* __restrict__ fpair,
                           float* __restrict__ agg, int n) {
    int wave = (blockIdx.x * blockDim.x + threadIdx.x) >> 6;
    int lane = threadIdx.x & 63;
    if (wave >= n) return;
    int e0 = __builtin_amdgcn_readfirstlane(off[wave]);
    int e1 = __builtin_amdgcn_readfirstlane(off[wave + 1]);
    const float FRS = 1.f / 1048576.f;
    float acc[4] = {0.f, 0.f, 0.f, 0.f};
    int e = e0;
    for (; e + 8 <= e1; e += 8) {
        float mv[8], wv[8];
#pragma unroll
        for (int u = 0; u < 8; ++u) {
            int2 pd = edata[e + u];
            int px = __builtin_amdgcn_readfirstlane(pd.x);
            int py = __builtin_amdgcn_readfirstlane(pd.y);
            int s = px & 0x1FFFF;
            unsigned ti = ((unsigned)py) >> 20;
            float fr = (float)(py & 0xFFFFF) * FRS;
            mv[u] = __half2float(m[(size_t)s * 64 + lane]);
            float2 wf = __half22float2(fpair[(size_t)ti * 64 + lane]);
            wv[u] = fmaf(fr, wf.y - wf.x, wf.x);
        }
#pragma unroll
        for (int u = 0; u < 8; ++u) acc[u & 3] = fmaf(mv[u], wv[u], acc[u & 3]);
    }
    for (; e + 4 <= e1; e += 4) {
        float mv[4], wv[4];
#pragma unroll
        for (int u = 0; u < 4; ++u) {
            int2 pd = edata[e + u];
            int px = __builtin_amdgcn_readfirstlane(pd.x);
            int py = __builtin_amdgcn_readfirstlane(pd.y);
            int s = px & 0x1FFFF;
            unsigned ti = ((unsigned)py) >> 20;
            float fr = (float)(py & 0xFFFFF) * FRS;
            mv[u] = __half2float(m[(size_t)s * 64 + lane]);
            float2 wf = __half22float2(fpair[(size_t)ti * 64 + lane]);
            wv[u] = fmaf(fr, wf.y - wf.x, wf.x);
        }
#pragma unroll
        for (int u = 0; u < 4; ++u) acc[u] = fmaf(mv[u], wv[u], acc[u]);
    }
    for (; e < e1; ++e) {
        int2 pd = edata[e];
        int px = __builtin_amdgcn_readfirstlane(pd.x);
        int py = __builtin_amdgcn_readfirstlane(pd.y);
        int s = px & 0x1FFFF;
        unsigned ti = ((unsigned)py) >> 20;
        float fr = (float)(py & 0xFFFFF) * FRS;
        float mm = __half2float(m[(size_t)s * 64 + lane]);
        float2 wf = __half22float2(fpair[(size_t)ti * 64 + lane]);
        acc[0] = fmaf(mm, fmaf(fr, wf.y - wf.x, wf.x), acc[0]);
    }
    agg[(size_t)wave * 64 + lane] = (acc[0] + acc[1]) + (acc[2] + acc[3]);
}

// ------- fused 2-layer: out = ssp(in@W1+b1)@W2+b2 (+res) (+ next m) ----------
// quarter split; EMIT_M adds the node-local phase C (next interaction's
// m = out @ lw + lb) — the safe half of R12's fusion (no gather involved).
#define HSTR 65
template <bool RES, bool EMIT_M>
__global__ __launch_bounds__(256, 4)
void mm2_kernel(const float* __restrict__ in,
                const float* __restrict__ w1, const float* __restrict__ b1,
                const float* __restrict__ w2, const float* __restrict__ b2,
                const float* __restrict__ res, float* __restrict__ out,
                const float* __restrict__ lw, const float* __restrict__ lb,
                __half* __restrict__ mout, int n) {
    __shared__ float hl[64 * HSTR];
    int tid = threadIdx.x;
    int q = __builtin_amdgcn_readfirstlane(tid >> 6);   // 0..3, wave-uniform
    int nl = tid & 63;
    int node = blockIdx.x * 64 + nl;
    node = min(node, n - 1);

    const float4* in4 = (const float4*)(in + (size_t)node * 64);
    const float* w1q = w1 + q * 16;
    const float* b1q = b1 + q * 16;
    float acc[16];
#pragma unroll
    for (int j = 0; j < 16; ++j) acc[j] = b1q[j];
#pragma unroll 2
    for (int kk = 0; kk < 16; ++kk) {
        float4 xv = in4[kk];
        const float* w0 = w1q + kk * 256;
#pragma unroll
        for (int j = 0; j < 16; ++j) acc[j] = fmaf(xv.x, w0[j],       acc[j]);
#pragma unroll
        for (int j = 0; j < 16; ++j) acc[j] = fmaf(xv.y, w0[64 + j],  acc[j]);
#pragma unroll
        for (int j = 0; j < 16; ++j) acc[j] = fmaf(xv.z, w0[128 + j], acc[j]);
#pragma unroll
        for (int j = 0; j < 16; ++j) acc[j] = fmaf(xv.w, w0[192 + j], acc[j]);
    }
    float* hrow = hl + nl * HSTR + q * 16;
#pragma unroll
    for (int j = 0; j < 16; ++j) hrow[j] = ssp(acc[j]);
    __syncthreads();

    const float* hfull = hl + nl * HSTR;
    const float* w2q = w2 + q * 16;
    const float* b2q = b2 + q * 16;
    float acc2[16];
#pragma unroll
    for (int j = 0; j < 16; ++j) acc2[j] = b2q[j];
#pragma unroll 4
    for (int k = 0; k < 64; ++k) {
        float hk = hfull[k];
        const float* w0 = w2q + k * 64;
#pragma unroll
        for (int j = 0; j < 16; ++j) acc2[j] = fmaf(hk, w0[j], acc2[j]);
    }
    const float4* r4 = (const float4*)(res + (size_t)node * 64 + q * 16);
    float4* o4 = (float4*)(out + (size_t)node * 64 + q * 16);
    float4 vout[4];
#pragma unroll
    for (int c = 0; c < 4; ++c) {
        float4 v;
        v.x = acc2[4 * c];     v.y = acc2[4 * c + 1];
        v.z = acc2[4 * c + 2]; v.w = acc2[4 * c + 3];
        if constexpr (RES) {
            float4 rv = r4[c];
            v.x += rv.x; v.y += rv.y; v.z += rv.z; v.w += rv.w;
        }
        o4[c] = v;
        vout[c] = v;
    }
    if constexpr (EMIT_M) {
        __syncthreads();              // all hl reads of phase 2 done
#pragma unroll
        for (int c = 0; c < 4; ++c) {
            hrow[4 * c]     = vout[c].x;
            hrow[4 * c + 1] = vout[c].y;
            hrow[4 * c + 2] = vout[c].z;
            hrow[4 * c + 3] = vout[c].w;
        }
        __syncthreads();
        const float* lwq = lw + q * 16;
        float accm[16];
#pragma unroll
        for (int j = 0; j < 16; ++j) accm[j] = lb[q * 16 + j];
#pragma unroll 4
        for (int k = 0; k < 64; ++k) {
            float hk = hfull[k];
            const float* w0 = lwq + k * 64;
#pragma unroll
            for (int j = 0; j < 16; ++j) accm[j] = fmaf(hk, w0[j], accm[j]);
        }
        __half2* o2 = (__half2*)(mout + (size_t)node * 64 + q * 16);
#pragma unroll
        for (int c = 0; c < 8; ++c)
            o2[c] = __floats2half2_rn(accm[2 * c], accm[2 * c + 1]);
    }
}

// ---------------- scatter-mean pooling via binary search (batch sorted) -----
__global__ void pool_kernel(const float* __restrict__ h, const int* __restrict__ batch,
                            float* __restrict__ pooled, int n_nodes) {
    int g = blockIdx.x, j = threadIdx.x;   // block = 64
    int lo = 0, hi = n_nodes;
    while (lo < hi) { int mid = (lo + hi) >> 1; if (batch[mid] < g) lo = mid + 1; else hi = mid; }
    int start = lo;
    int lo2 = start, hi2 = n_nodes;
    while (lo2 < hi2) { int mid = (lo2 + hi2) >> 1; if (batch[mid] < g + 1) lo2 = mid + 1; else hi2 = mid; }
    int end = lo2;
    float acc = 0.f;
    for (int r = start; r < end; ++r) acc += h[(size_t)r * 64 + j];
    float cnt = (float)(end - start);
    pooled[(size_t)g * 64 + j] = acc / fmaxf(cnt, 1.f);
}

// ---------------- final graph head: 96 -> 128 -> 32 -> 1 --------------------
__global__ void post2_kernel(const float* __restrict__ pooled, const float* __restrict__ s4,
                             const int* __restrict__ solvent,
                             const float* __restrict__ w1, const float* __restrict__ b1,
                             const float* __restrict__ w2, const float* __restrict__ b2,
                             const float* __restrict__ w3, const float* __restrict__ b3,
                             float* __restrict__ out) {
    __shared__ float in96[96];
    __shared__ float l1[128];
    __shared__ float l2[32];
    int g = blockIdx.x, t = threadIdx.x;   // block = 128
    if (t < 64)      in96[t] = pooled[(size_t)g * 64 + t];
    else if (t < 96) in96[t] = s4[solvent[g] * 32 + (t - 64)];
    __syncthreads();
    float acc = b1[t];
    for (int k = 0; k < 96; ++k) acc = fmaf(in96[k], w1[k * 128 + t], acc);
    l1[t] = ssp(acc);
    __syncthreads();
    if (t < 32) {
        float a = b2[t];
        for (int k = 0; k < 128; ++k) a = fmaf(l1[k], w2[k * 32 + t], a);
        l2[t] = ssp(a);
    }
    __syncthreads();
    if (t < 32) {
        float p = l2[t] * w3[t];
        for (int o = 16; o >= 1; o >>= 1) p += __shfl_down(p, o);
        if (t == 0) out[g] = p + b3[0];
    }
}

extern "C" void kernel_launch(void* const* d_in, const int* in_sizes, int n_in,
                              void* d_out, int out_size, void* d_ws, size_t ws_size,
                              hipStream_t stream) {
    const float* pos      = (const float*)d_in[0];
    const int*   ei       = (const int*)d_in[1];
    const int*   z        = (const int*)d_in[2];
    const int*   batch    = (const int*)d_in[3];
    const int*   solvent  = (const int*)d_in[4];
    const float* emb_z    = (const float*)d_in[5];
    const float* emb_solv = (const float*)d_in[6];
    const float* solv_w1  = (const float*)d_in[7];  const float* solv_b1 = (const float*)d_in[8];
    const float* solv_w2  = (const float*)d_in[9];  const float* solv_b2 = (const float*)d_in[10];
    const float* lin1_w   = (const float*)d_in[11]; const float* lin1_b  = (const float*)d_in[12];
    const float* mlp_w1   = (const float*)d_in[13]; const float* mlp_b1  = (const float*)d_in[14];
    const float* mlp_w2   = (const float*)d_in[15]; const float* mlp_b2  = (const float*)d_in[16];
    const float* filt_w1  = (const float*)d_in[17]; const float* filt_b1 = (const float*)d_in[18];
    const float* filt_w2  = (const float*)d_in[19]; const float* filt_b2 = (const float*)d_in[20];
    const float* post_w1  = (const float*)d_in[21]; const float* post_b1 = (const float*)d_in[22];
    const float* post_w2  = (const float*)d_in[23]; const float* post_b2 = (const float*)d_in[24];
    const float* p2w1 = (const float*)d_in[25]; const float* p2b1 = (const float*)d_in[26];
    const float* p2w2 = (const float*)d_in[27]; const float* p2b2 = (const float*)d_in[28];
    const float* p2w3 = (const float*)d_in[29]; const float* p2b3 = (const float*)d_in[30];
    float* out = (float*)d_out;

    const int N = in_sizes[2];
    const int E = in_sizes[1] / 2;
    const int G = in_sizes[4];
    const int NBUCK = (N + (1 << SBITS) - 1) >> SBITS;

    char* wp = (char*)d_ws;
    auto alloc = [&](size_t bytes) -> void* {
        void* r = (void*)wp;
        wp += (bytes + 255) & ~(size_t)255;
        return r;
    };
    int2*    stg    = (int2*)   alloc((size_t)E * 8);
    int2*    edata  = (int2*)   alloc((size_t)E * 8);
    int*     bcnt   = (int*)    alloc(256 * 4);
    int*     bbase  = (int*)    alloc(257 * 4);
    int*     bcur   = (int*)    alloc(256 * 4);
    int*     off    = (int*)    alloc((size_t)(N + 1) * 4);
    float*   ftab   = (float*)  alloc((size_t)2 * ROWS * 64 * 4);
    __half2* fpair  = (__half2*)alloc((size_t)2 * TABN * 64 * 4);
    float*   s4     = (float*)  alloc(4 * 32 * 4);
    float*   x      = (float*)  alloc((size_t)N * 64 * 4);
    __half*  m_h    = (__half*) alloc((size_t)N * 64 * 2);
    __half*  m_h2   = (__half*) alloc((size_t)N * 64 * 2);
    float*   agg    = (float*)  alloc((size_t)N * 64 * 4);
    float*   hbuf   = (float*)  alloc((size_t)N * 64 * 4);
    float*   pooled = (float*)  alloc((size_t)G * 64 * 4);
    (void)ws_size; (void)n_in; (void)out_size;

    hipMemsetAsync(bcnt, 0, 256 * 4, stream);

    ftab_kernel<<<dim3(ROWS, 2), 64, 0, stream>>>(filt_w1, filt_b1, filt_w2, filt_b2, ftab);
    fpack_kernel<<<dim3(TABN, 2), 64, 0, stream>>>(ftab, fpair);
    bhist_kernel<<<512, 256, 0, stream>>>(ei, bcnt, E);
    bscan_kernel<<<1, 256, 0, stream>>>(bcnt, bbase, bcur, NBUCK);
    stage_kernel<<<(E + TILE - 1) / TILE, 256, 0, stream>>>(pos, ei, bcur, stg, E, NBUCK);
    place_kernel<<<NBUCK, 256, 0, stream>>>(stg, bbase, off, edata, N, NBUCK);
    embed_kernel<<<((size_t)N * 16 + 255) / 256, 256, 0, stream>>>(z, emb_z, x, N);
    solv_kernel<<<1, 256, 0, stream>>>(emb_solv, solv_w1, solv_b1, solv_w2, solv_b2, s4);

    int mmg = (N + 63) / 64;
    // interaction 0: m0 = x @ lin1[0]
    mm1h_kernel<<<mmg, 256, 0, stream>>>(x, lin1_w, lin1_b, m_h, N);
    agg_kernel<<<(N + 3) / 4, 256, 0, stream>>>(off, edata, m_h, fpair, agg, N);
    // MLP + residual -> x, and emit m1 = x @ lin1[1] (node-local fusion)
    mm2_kernel<true, true><<<mmg, 256, 0, stream>>>(agg, mlp_w1, mlp_b1, mlp_w2, mlp_b2,
                                                    x, x, lin1_w + 4096, lin1_b + 64,
                                                    m_h2, N);
    // interaction 1
    agg_kernel<<<(N + 3) / 4, 256, 0, stream>>>(off, edata, m_h2,
                                                fpair + (size_t)TABN * 64, agg, N);
    mm2_kernel<true, false><<<mmg, 256, 0, stream>>>(agg, mlp_w1 + 4096, mlp_b1 + 64,
                                                     mlp_w2 + 4096, mlp_b2 + 64,
                                                     x, x, nullptr, nullptr, nullptr, N);
    // post MLP: h = ssp(x@pw1+b1)@pw2+b2
    mm2_kernel<false, false><<<mmg, 256, 0, stream>>>(x, post_w1, post_b1, post_w2, post_b2,
                                                      nullptr, hbuf, nullptr, nullptr,
                                                      nullptr, N);

    pool_kernel<<<G, 64, 0, stream>>>(hbuf, batch, pooled, N);
    post2_kernel<<<G, 128, 0, stream>>>(pooled, s4, solvent, p2w1, p2b1, p2w2, p2b2,
                                        p2w3, p2b3, out);
}

// Round 14
// 362.949 us; speedup vs baseline: 1.2794x; 1.0253x over previous
//
#include <hip/hip_runtime.h>
#include <hip/hip_bf16.h>
#include <hip/hip_fp16.h>

#define TABN   4096
#define ROWS   (TABN + 1)           // table rows per interaction
#define DMAX   6.5f
#define DELTA  (DMAX / (float)TABN)
#define INVD   ((float)TABN / DMAX)
#define LOG2F_ 0.6931471805599453f
#define SBITS  9                    // 512 tgt-nodes per bucket
#define TILE   2048                 // edges per stage tile

__device__ __forceinline__ float ssp(float x) {
    // shifted softplus via fast-math intrinsics: log(1+e^x) - log(2)
    return fmaxf(x, 0.f) + __logf(1.f + __expf(-fabsf(x))) - LOG2F_;
}

// ---------------- filter lookup table: W_i(d) for d = t*DELTA ----------------
__global__ void ftab_kernel(const float* __restrict__ fw1, const float* __restrict__ fb1,
                            const float* __restrict__ fw2, const float* __restrict__ fb2,
                            float* __restrict__ ftab) {
    int t = blockIdx.x;          // 0..ROWS-1
    int i = blockIdx.y;          // interaction 0/1
    int j = threadIdx.x;         // 0..63 channel
    float d = (float)t * DELTA;
    float acc = fb1[i * 64 + j];
    for (int k = 0; k < 51; ++k) {
        float u = d - 0.1f * (float)k;
        float r = __expf(-10.f * u * u);
        acc = fmaf(r, fw1[((size_t)i * 51 + k) * 64 + j], acc);
    }
    __shared__ float h[64];
    h[j] = ssp(acc);
    __syncthreads();
    float o = fb2[i * 64 + j];
    for (int k = 0; k < 64; ++k)
        o = fmaf(h[k], fw2[((size_t)i * 64 + k) * 64 + j], o);
    ftab[((size_t)i * ROWS + t) * 64 + j] = o;
}

// ------- pack lerp endpoints as fp16 pair: 4B/entry, 1MB/interaction --------
__global__ void fpack_kernel(const float* __restrict__ ftab, __half2* __restrict__ fpair) {
    int t = blockIdx.x, i = blockIdx.y, j = threadIdx.x;
    const float* r = ftab + ((size_t)i * ROWS + t) * 64;
    fpair[((size_t)i * TABN + t) * 64 + j] = __floats2half2_rn(r[j], r[j + 64]);
}

// ---------------- bucket histogram (LDS-privatized) ----------------
__global__ void bhist_kernel(const int* __restrict__ ei, int* __restrict__ bcnt, int E) {
    __shared__ int h[256];
    int tid = threadIdx.x;
    h[tid] = 0;
    __syncthreads();
    for (int e = blockIdx.x * blockDim.x + tid; e < E; e += gridDim.x * blockDim.x)
        atomicAdd(&h[ei[E + e] >> SBITS], 1);
    __syncthreads();
    if (h[tid]) atomicAdd(&bcnt[tid], h[tid]);
}

// ---------------- bucket exclusive scan (parallel, one block) ----------------
__global__ void bscan_kernel(const int* __restrict__ bcnt, int* __restrict__ bbase,
                             int* __restrict__ bcur, int nbuck) {
    __shared__ int sm[256];
    int tid = threadIdx.x;
    int v = (tid < nbuck) ? bcnt[tid] : 0;
    sm[tid] = v;
    __syncthreads();
    for (int o = 1; o < 256; o <<= 1) {
        int t = (tid >= o) ? sm[tid - o] : 0;
        __syncthreads();
        sm[tid] += t;
        __syncthreads();
    }
    if (tid < nbuck) { bbase[tid] = sm[tid] - v; bcur[tid] = sm[tid] - v; }
    if (tid == 255) bbase[nbuck] = sm[255];
}

// ------- stage: LDS multisplit of edge tiles into bucket-ordered stg ---------
// payload: w0 = src | (t&511)<<17 ; w1 = ti<<20 | frac_q20
__global__ __launch_bounds__(256, 4)
void stage_kernel(const float* __restrict__ pos, const int* __restrict__ ei,
                  int* __restrict__ bcur, int2* __restrict__ stg, int E, int nbuck) {
    __shared__ int hist[256], loff[256], gbase[256], sc[256];
    __shared__ int2 sp[TILE];
    __shared__ short sb[TILE];
    int tid = threadIdx.x;
    int tile0 = blockIdx.x * TILE;
    int cnt = min(TILE, E - tile0);
    hist[tid] = 0;
    __syncthreads();
    int myrank[8], myb[8]; int2 mypay[8];
#pragma unroll
    for (int u = 0; u < 8; ++u) {
        int i = u * 256 + tid;
        myb[u] = -1;
        if (i < cnt) {
            int e = tile0 + i;
            int s = ei[e], t = ei[E + e];
            float dx = pos[3 * s]     - pos[3 * t];
            float dy = pos[3 * s + 1] - pos[3 * t + 1];
            float dz = pos[3 * s + 2] - pos[3 * t + 2];
            float d = sqrtf(dx * dx + dy * dy + dz * dz);
            float ds = fminf(d, DMAX) * INVD;
            int ti = min((int)ds, TABN - 1);
            int frq = min((int)((ds - (float)ti) * 1048576.f), 1048575);
            mypay[u] = make_int2(s | ((t & 511) << 17), (ti << 20) | frq);
            myb[u] = t >> SBITS;
            myrank[u] = atomicAdd(&hist[myb[u]], 1);
        }
    }
    __syncthreads();
    sc[tid] = hist[tid];
    __syncthreads();
    for (int o = 1; o < 256; o <<= 1) {
        int v = (tid >= o) ? sc[tid - o] : 0;
        __syncthreads();
        sc[tid] += v;
        __syncthreads();
    }
    loff[tid] = sc[tid] - hist[tid];
    if (tid < nbuck && hist[tid] > 0) gbase[tid] = atomicAdd(&bcur[tid], hist[tid]);
    __syncthreads();
#pragma unroll
    for (int u = 0; u < 8; ++u)
        if (myb[u] >= 0) {
            int idx = loff[myb[u]] + myrank[u];
            sp[idx] = mypay[u];
            sb[idx] = (short)myb[u];
        }
    __syncthreads();
    for (int i = tid; i < cnt; i += 256) {
        int b = sb[i];
        stg[gbase[b] + (i - loff[b])] = sp[i];
    }
}

// ------- place: per bucket, exact CSR placement with LDS-only atomics --------
__global__ __launch_bounds__(256)
void place_kernel(const int2* __restrict__ stg, const int* __restrict__ bbase,
                  int* __restrict__ off, int2* __restrict__ edata, int n, int nbuck) {
    int b = blockIdx.x;
    int n0 = b << SBITS;
    int nn = min(512, n - n0);
    int q0 = bbase[b], q1 = bbase[b + 1];
    __shared__ int cnt[512], cur[512], sc[256];
    int tid = threadIdx.x;
    cnt[tid] = 0; cnt[tid + 256] = 0;
    __syncthreads();
    for (int q = q0 + tid; q < q1; q += 256)
        atomicAdd(&cnt[(stg[q].x >> 17) & 511], 1);
    __syncthreads();
    int c0 = cnt[2 * tid], c1 = cnt[2 * tid + 1];
    int s = c0 + c1;
    sc[tid] = s;
    __syncthreads();
    for (int o = 1; o < 256; o <<= 1) {
        int v = (tid >= o) ? sc[tid - o] : 0;
        __syncthreads();
        sc[tid] += v;
        __syncthreads();
    }
    int run = sc[tid] - s;        // exclusive over node pairs
    cur[2 * tid] = run;
    cur[2 * tid + 1] = run + c0;
    if (2 * tid < nn)     off[n0 + 2 * tid]     = q0 + run;
    if (2 * tid + 1 < nn) off[n0 + 2 * tid + 1] = q0 + run + c0;
    if (b == nbuck - 1 && tid == 0) off[n] = q1;
    __syncthreads();
    for (int q = q0 + tid; q < q1; q += 256) {
        int2 v = stg[q];
        int p = atomicAdd(&cur[(v.x >> 17) & 511], 1);
        edata[q0 + p] = v;
    }
}

// ---------------- x = emb_z[z] (coalesced materialization for residual) -----
__global__ void embed_kernel(const int* __restrict__ z, const float* __restrict__ emb,
                             float* __restrict__ x, int n) {
    int idx = blockIdx.x * blockDim.x + threadIdx.x;   // over n*16 float4 chunks
    if (idx >= n * 16) return;
    int node = idx >> 4, c = idx & 15;
    ((float4*)x)[idx] = ((const float4*)emb)[z[node] * 16 + c];
}

// ---------------- solvent head for the 4 unique solvent rows ----------------
__global__ void solv_kernel(const float* __restrict__ emb_solv,
                            const float* __restrict__ w1, const float* __restrict__ b1,
                            const float* __restrict__ w2, const float* __restrict__ b2,
                            float* __restrict__ s4) {
    __shared__ float h[4][64];
    int t = threadIdx.x, r = t >> 6, j = t & 63;
    float acc = b1[j];
    for (int k = 0; k < 64; ++k) acc = fmaf(emb_solv[r * 64 + k], w1[k * 64 + j], acc);
    h[r][j] = ssp(acc);
    __syncthreads();
    if (j < 32) {
        float a = b2[j];
        for (int k = 0; k < 64; ++k) a = fmaf(h[r][k], w2[k * 32 + j], a);
        s4[r * 32 + j] = a;
    }
}

// ------------- m0 = emb_z[z]@W+b, fp16 out; reads L1-resident emb table -----
__global__ __launch_bounds__(256, 4)
void mm1h_kernel(const int* __restrict__ z, const float* __restrict__ emb,
                 const float* __restrict__ w, const float* __restrict__ b,
                 __half* __restrict__ out, int n) {
    int tid = threadIdx.x;
    int q = __builtin_amdgcn_readfirstlane(tid >> 6);   // 0..3, wave-uniform
    int node = blockIdx.x * 64 + (tid & 63);
    node = min(node, n - 1);                    // no divergent return
    int zi = z[node];
    const float4* in4 = (const float4*)(emb + (size_t)zi * 64);  // 25KB table: L1 hit
    const float* wq = w + q * 16;
    const float* bq = b + q * 16;
    float acc[16];
#pragma unroll
    for (int j = 0; j < 16; ++j) acc[j] = bq[j];
#pragma unroll 2
    for (int kk = 0; kk < 16; ++kk) {
        float4 xv = in4[kk];
        const float* w0 = wq + kk * 256;
#pragma unroll
        for (int j = 0; j < 16; ++j) acc[j] = fmaf(xv.x, w0[j],       acc[j]);
#pragma unroll
        for (int j = 0; j < 16; ++j) acc[j] = fmaf(xv.y, w0[64 + j],  acc[j]);
#pragma unroll
        for (int j = 0; j < 16; ++j) acc[j] = fmaf(xv.z, w0[128 + j], acc[j]);
#pragma unroll
        for (int j = 0; j < 16; ++j) acc[j] = fmaf(xv.w, w0[192 + j], acc[j]);
    }
    __half2* o2 = (__half2*)(out + (size_t)node * 64 + q * 16);
#pragma unroll
    for (int c = 0; c < 8; ++c)
        o2[c] = __floats2half2_rn(acc[2 * c], acc[2 * c + 1]);
}

// ---------------- per-node aggregation: agg[t] = sum_e m[src]*W(d) ----------
// wave per tgt node (100k waves of TLP), lane = channel; edata words
// readfirstlane'd -> SALU decode; m fp16 rows, fpair __half2 L2-resident;
// OUTPUT fp16 (feeds only mm2 layer 1).
__global__ void agg_kernel(const int* __restrict__ off, const int2* __restrict__ edata,
                           const __half* __restrict__ m, const __half2* __restrict__ fpair,
                           __half* __restrict__ agg, int n) {
    int wave = (blockIdx.x * blockDim.x + threadIdx.x) >> 6;
    int lane = threadIdx.x & 63;
    if (wave >= n) return;
    int e0 = __builtin_amdgcn_readfirstlane(off[wave]);
    int e1 = __builtin_amdgcn_readfirstlane(off[wave + 1]);
    const float FRS = 1.f / 1048576.f;
    float acc[4] = {0.f, 0.f, 0.f, 0.f};
    int e = e0;
    for (; e + 8 <= e1; e += 8) {
        float mv[8], wv[8];
#pragma unroll
        for (int u = 0; u < 8; ++u) {
            int2 pd = edata[e + u];
            int px = __builtin_amdgcn_readfirstlane(pd.x);
            int py = __builtin_amdgcn_readfirstlane(pd.y);
            int s = px & 0x1FFFF;
            unsigned ti = ((unsigned)py) >> 20;
            float fr = (float)(py & 0xFFFFF) * FRS;
            mv[u] = __half2float(m[(size_t)s * 64 + lane]);
            float2 wf = __half22float2(fpair[(size_t)ti * 64 + lane]);
            wv[u] = fmaf(fr, wf.y - wf.x, wf.x);
        }
#pragma unroll
        for (int u = 0; u < 8; ++u) acc[u & 3] = fmaf(mv[u], wv[u], acc[u & 3]);
    }
    for (; e + 4 <= e1; e += 4) {
        float mv[4], wv[4];
#pragma unroll
        for (int u = 0; u < 4; ++u) {
            int2 pd = edata[e + u];
            int px = __builtin_amdgcn_readfirstlane(pd.x);
            int py = __builtin_amdgcn_readfirstlane(pd.y);
            int s = px & 0x1FFFF;
            unsigned ti = ((unsigned)py) >> 20;
            float fr = (float)(py & 0xFFFFF) * FRS;
            mv[u] = __half2float(m[(size_t)s * 64 + lane]);
            float2 wf = __half22float2(fpair[(size_t)ti * 64 + lane]);
            wv[u] = fmaf(fr, wf.y - wf.x, wf.x);
        }
#pragma unroll
        for (int u = 0; u < 4; ++u) acc[u] = fmaf(mv[u], wv[u], acc[u]);
    }
    for (; e < e1; ++e) {
        int2 pd = edata[e];
        int px = __builtin_amdgcn_readfirstlane(pd.x);
        int py = __builtin_amdgcn_readfirstlane(pd.y);
        int s = px & 0x1FFFF;
        unsigned ti = ((unsigned)py) >> 20;
        float fr = (float)(py & 0xFFFFF) * FRS;
        float mm = __half2float(m[(size_t)s * 64 + lane]);
        float2 wf = __half22float2(fpair[(size_t)ti * 64 + lane]);
        acc[0] = fmaf(mm, fmaf(fr, wf.y - wf.x, wf.x), acc[0]);
    }
    agg[(size_t)wave * 64 + lane] = __float2half((acc[0] + acc[1]) + (acc[2] + acc[3]));
}

// ------- fused 2-layer: out = ssp(in@W1+b1)@W2+b2 (+res) (+ next m) ----------
// quarter split; INH: fp16 input rows; OUTH: fp16 output; EMIT_M: also emit
// next interaction's m (node-local fusion only — R12 lesson: never fuse the
// gather).
#define HSTR 65
template <bool INH, bool RES, bool EMIT_M, bool OUTH>
__global__ __launch_bounds__(256, 4)
void mm2_kernel(const void* __restrict__ in_,
                const float* __restrict__ w1, const float* __restrict__ b1,
                const float* __restrict__ w2, const float* __restrict__ b2,
                const float* __restrict__ res, void* __restrict__ out_,
                const float* __restrict__ lw, const float* __restrict__ lb,
                __half* __restrict__ mout, int n) {
    __shared__ float hl[64 * HSTR];
    int tid = threadIdx.x;
    int q = __builtin_amdgcn_readfirstlane(tid >> 6);   // 0..3, wave-uniform
    int nl = tid & 63;
    int node = blockIdx.x * 64 + nl;
    node = min(node, n - 1);

    const float* w1q = w1 + q * 16;
    const float* b1q = b1 + q * 16;
    float acc[16];
#pragma unroll
    for (int j = 0; j < 16; ++j) acc[j] = b1q[j];
    if constexpr (INH) {
        const float4* in4 = (const float4*)((const __half*)in_ + (size_t)node * 64);
#pragma unroll 1
        for (int kk = 0; kk < 8; ++kk) {
            float4 raw = in4[kk];
            const __half2* hp = (const __half2*)&raw;
            float xs[8];
#pragma unroll
            for (int p = 0; p < 4; ++p) {
                float2 f = __half22float2(hp[p]);
                xs[2 * p] = f.x; xs[2 * p + 1] = f.y;
            }
#pragma unroll
            for (int r = 0; r < 8; ++r) {
                const float* w0 = w1q + (kk * 8 + r) * 64;
#pragma unroll
                for (int j = 0; j < 16; ++j) acc[j] = fmaf(xs[r], w0[j], acc[j]);
            }
        }
    } else {
        const float4* in4 = (const float4*)((const float*)in_ + (size_t)node * 64);
#pragma unroll 2
        for (int kk = 0; kk < 16; ++kk) {
            float4 xv = in4[kk];
            const float* w0 = w1q + kk * 256;
#pragma unroll
            for (int j = 0; j < 16; ++j) acc[j] = fmaf(xv.x, w0[j],       acc[j]);
#pragma unroll
            for (int j = 0; j < 16; ++j) acc[j] = fmaf(xv.y, w0[64 + j],  acc[j]);
#pragma unroll
            for (int j = 0; j < 16; ++j) acc[j] = fmaf(xv.z, w0[128 + j], acc[j]);
#pragma unroll
            for (int j = 0; j < 16; ++j) acc[j] = fmaf(xv.w, w0[192 + j], acc[j]);
        }
    }
    float* hrow = hl + nl * HSTR + q * 16;
#pragma unroll
    for (int j = 0; j < 16; ++j) hrow[j] = ssp(acc[j]);
    __syncthreads();

    const float* hfull = hl + nl * HSTR;
    const float* w2q = w2 + q * 16;
    const float* b2q = b2 + q * 16;
    float acc2[16];
#pragma unroll
    for (int j = 0; j < 16; ++j) acc2[j] = b2q[j];
#pragma unroll 8
    for (int k = 0; k < 64; ++k) {
        float hk = hfull[k];
        const float* w0 = w2q + k * 64;
#pragma unroll
        for (int j = 0; j < 16; ++j) acc2[j] = fmaf(hk, w0[j], acc2[j]);
    }
    if constexpr (RES) {
        const float4* r4 = (const float4*)(res + (size_t)node * 64 + q * 16);
#pragma unroll
        for (int c = 0; c < 4; ++c) {
            float4 rv = r4[c];
            acc2[4 * c]     += rv.x; acc2[4 * c + 1] += rv.y;
            acc2[4 * c + 2] += rv.z; acc2[4 * c + 3] += rv.w;
        }
    }
    if constexpr (OUTH) {
        __half2* o2 = (__half2*)((__half*)out_ + (size_t)node * 64 + q * 16);
#pragma unroll
        for (int c = 0; c < 8; ++c)
            o2[c] = __floats2half2_rn(acc2[2 * c], acc2[2 * c + 1]);
    } else {
        float4* o4 = (float4*)((float*)out_ + (size_t)node * 64 + q * 16);
#pragma unroll
        for (int c = 0; c < 4; ++c)
            o4[c] = make_float4(acc2[4 * c], acc2[4 * c + 1],
                                acc2[4 * c + 2], acc2[4 * c + 3]);
    }
    if constexpr (EMIT_M) {
        __syncthreads();              // all hl reads of phase 2 done
#pragma unroll
        for (int j = 0; j < 16; ++j) hrow[j] = acc2[j];
        __syncthreads();
        const float* lwq = lw + q * 16;
        float accm[16];
#pragma unroll
        for (int j = 0; j < 16; ++j) accm[j] = lb[q * 16 + j];
#pragma unroll 8
        for (int k = 0; k < 64; ++k) {
            float hk = hfull[k];
            const float* w0 = lwq + k * 64;
#pragma unroll
            for (int j = 0; j < 16; ++j) accm[j] = fmaf(hk, w0[j], accm[j]);
        }
        __half2* o2 = (__half2*)(mout + (size_t)node * 64 + q * 16);
#pragma unroll
        for (int c = 0; c < 8; ++c)
            o2[c] = __floats2half2_rn(accm[2 * c], accm[2 * c + 1]);
    }
}

// ---------------- scatter-mean pooling (fp16 input, batch sorted) -----------
__global__ void pool_kernel(const __half* __restrict__ h, const int* __restrict__ batch,
                            float* __restrict__ pooled, int n_nodes) {
    int g = blockIdx.x, j = threadIdx.x;   // block = 64
    int lo = 0, hi = n_nodes;
    while (lo < hi) { int mid = (lo + hi) >> 1; if (batch[mid] < g) lo = mid + 1; else hi = mid; }
    int start = lo;
    int lo2 = start, hi2 = n_nodes;
    while (lo2 < hi2) { int mid = (lo2 + hi2) >> 1; if (batch[mid] < g + 1) lo2 = mid + 1; else hi2 = mid; }
    int end = lo2;
    float acc = 0.f;
    for (int r = start; r < end; ++r) acc += __half2float(h[(size_t)r * 64 + j]);
    float cnt = (float)(end - start);
    pooled[(size_t)g * 64 + j] = acc / fmaxf(cnt, 1.f);
}

// ---------------- final graph head: 96 -> 128 -> 32 -> 1 --------------------
__global__ void post2_kernel(const float* __restrict__ pooled, const float* __restrict__ s4,
                             const int* __restrict__ solvent,
                             const float* __restrict__ w1, const float* __restrict__ b1,
                             const float* __restrict__ w2, const float* __restrict__ b2,
                             const float* __restrict__ w3, const float* __restrict__ b3,
                             float* __restrict__ out) {
    __shared__ float in96[96];
    __shared__ float l1[128];
    __shared__ float l2[32];
    int g = blockIdx.x, t = threadIdx.x;   // block = 128
    if (t < 64)      in96[t] = pooled[(size_t)g * 64 + t];
    else if (t < 96) in96[t] = s4[solvent[g] * 32 + (t - 64)];
    __syncthreads();
    float acc = b1[t];
    for (int k = 0; k < 96; ++k) acc = fmaf(in96[k], w1[k * 128 + t], acc);
    l1[t] = ssp(acc);
    __syncthreads();
    if (t < 32) {
        float a = b2[t];
        for (int k = 0; k < 128; ++k) a = fmaf(l1[k], w2[k * 32 + t], a);
        l2[t] = ssp(a);
    }
    __syncthreads();
    if (t < 32) {
        float p = l2[t] * w3[t];
        for (int o = 16; o >= 1; o >>= 1) p += __shfl_down(p, o);
        if (t == 0) out[g] = p + b3[0];
    }
}

extern "C" void kernel_launch(void* const* d_in, const int* in_sizes, int n_in,
                              void* d_out, int out_size, void* d_ws, size_t ws_size,
                              hipStream_t stream) {
    const float* pos      = (const float*)d_in[0];
    const int*   ei       = (const int*)d_in[1];
    const int*   z        = (const int*)d_in[2];
    const int*   batch    = (const int*)d_in[3];
    const int*   solvent  = (const int*)d_in[4];
    const float* emb_z    = (const float*)d_in[5];
    const float* emb_solv = (const float*)d_in[6];
    const float* solv_w1  = (const float*)d_in[7];  const float* solv_b1 = (const float*)d_in[8];
    const float* solv_w2  = (const float*)d_in[9];  const float* solv_b2 = (const float*)d_in[10];
    const float* lin1_w   = (const float*)d_in[11]; const float* lin1_b  = (const float*)d_in[12];
    const float* mlp_w1   = (const float*)d_in[13]; const float* mlp_b1  = (const float*)d_in[14];
    const float* mlp_w2   = (const float*)d_in[15]; const float* mlp_b2  = (const float*)d_in[16];
    const float* filt_w1  = (const float*)d_in[17]; const float* filt_b1 = (const float*)d_in[18];
    const float* filt_w2  = (const float*)d_in[19]; const float* filt_b2 = (const float*)d_in[20];
    const float* post_w1  = (const float*)d_in[21]; const float* post_b1 = (const float*)d_in[22];
    const float* post_w2  = (const float*)d_in[23]; const float* post_b2 = (const float*)d_in[24];
    const float* p2w1 = (const float*)d_in[25]; const float* p2b1 = (const float*)d_in[26];
    const float* p2w2 = (const float*)d_in[27]; const float* p2b2 = (const float*)d_in[28];
    const float* p2w3 = (const float*)d_in[29]; const float* p2b3 = (const float*)d_in[30];
    float* out = (float*)d_out;

    const int N = in_sizes[2];
    const int E = in_sizes[1] / 2;
    const int G = in_sizes[4];
    const int NBUCK = (N + (1 << SBITS) - 1) >> SBITS;

    char* wp = (char*)d_ws;
    auto alloc = [&](size_t bytes) -> void* {
        void* r = (void*)wp;
        wp += (bytes + 255) & ~(size_t)255;
        return r;
    };
    int2*    stg    = (int2*)   alloc((size_t)E * 8);
    int2*    edata  = (int2*)   alloc((size_t)E * 8);
    int*     bcnt   = (int*)    alloc(256 * 4);
    int*     bbase  = (int*)    alloc(257 * 4);
    int*     bcur   = (int*)    alloc(256 * 4);
    int*     off    = (int*)    alloc((size_t)(N + 1) * 4);
    float*   ftab   = (float*)  alloc((size_t)2 * ROWS * 64 * 4);
    __half2* fpair  = (__half2*)alloc((size_t)2 * TABN * 64 * 4);
    float*   s4     = (float*)  alloc(4 * 32 * 4);
    float*   x      = (float*)  alloc((size_t)N * 64 * 4);
    __half*  m_h    = (__half*) alloc((size_t)N * 64 * 2);
    __half*  m_h2   = (__half*) alloc((size_t)N * 64 * 2);
    __half*  agg_h  = (__half*) alloc((size_t)N * 64 * 2);
    __half*  hbuf   = (__half*) alloc((size_t)N * 64 * 2);
    float*   pooled = (float*)  alloc((size_t)G * 64 * 4);
    (void)ws_size; (void)n_in; (void)out_size;

    hipMemsetAsync(bcnt, 0, 256 * 4, stream);

    ftab_kernel<<<dim3(ROWS, 2), 64, 0, stream>>>(filt_w1, filt_b1, filt_w2, filt_b2, ftab);
    fpack_kernel<<<dim3(TABN, 2), 64, 0, stream>>>(ftab, fpair);
    bhist_kernel<<<512, 256, 0, stream>>>(ei, bcnt, E);
    bscan_kernel<<<1, 256, 0, stream>>>(bcnt, bbase, bcur, NBUCK);
    stage_kernel<<<(E + TILE - 1) / TILE, 256, 0, stream>>>(pos, ei, bcur, stg, E, NBUCK);
    place_kernel<<<NBUCK, 256, 0, stream>>>(stg, bbase, off, edata, N, NBUCK);
    embed_kernel<<<((size_t)N * 16 + 255) / 256, 256, 0, stream>>>(z, emb_z, x, N);
    solv_kernel<<<1, 256, 0, stream>>>(emb_solv, solv_w1, solv_b1, solv_w2, solv_b2, s4);

    int mmg = (N + 63) / 64;
    // interaction 0: m0 = emb_z[z] @ lin1[0]  (table is L1-resident)
    mm1h_kernel<<<mmg, 256, 0, stream>>>(z, emb_z, lin1_w, lin1_b, m_h, N);
    agg_kernel<<<(N + 3) / 4, 256, 0, stream>>>(off, edata, m_h, fpair, agg_h, N);
    // MLP + residual -> x, and emit m1 = x @ lin1[1] (node-local fusion)
    mm2_kernel<true, true, true, false><<<mmg, 256, 0, stream>>>(
        agg_h, mlp_w1, mlp_b1, mlp_w2, mlp_b2, x, x,
        lin1_w + 4096, lin1_b + 64, m_h2, N);
    // interaction 1
    agg_kernel<<<(N + 3) / 4, 256, 0, stream>>>(off, edata, m_h2,
                                                fpair + (size_t)TABN * 64, agg_h, N);
    mm2_kernel<true, true, false, false><<<mmg, 256, 0, stream>>>(
        agg_h, mlp_w1 + 4096, mlp_b1 + 64, mlp_w2 + 4096, mlp_b2 + 64, x, x,
        nullptr, nullptr, nullptr, N);
    // post MLP: hbuf = ssp(x@pw1+b1)@pw2+b2 (fp16 out, feeds pool only)
    mm2_kernel<false, false, false, true><<<mmg, 256, 0, stream>>>(
        x, post_w1, post_b1, post_w2, post_b2, nullptr, hbuf,
        nullptr, nullptr, nullptr, N);

    pool_kernel<<<G, 64, 0, stream>>>(hbuf, batch, pooled, N);
    post2_kernel<<<G, 128, 0, stream>>>(pooled, s4, solvent, p2w1, p2b1, p2w2, p2b2,
                                        p2w3, p2b3, out);
}

// Round 15
// 333.365 us; speedup vs baseline: 1.3929x; 1.0887x over previous
//
#include <hip/hip_runtime.h>
#include <hip/hip_bf16.h>
#include <hip/hip_fp16.h>

#define TABN   4096
#define ROWS   (TABN + 1)           // table rows per interaction
#define DMAX   6.5f
#define DELTA  (DMAX / (float)TABN)
#define INVD   ((float)TABN / DMAX)
#define LOG2F_ 0.6931471805599453f
#define SBITS  9                    // 512 tgt-nodes per bucket
#define TILE   2048                 // edges per stage tile

typedef _Float16 f16x8 __attribute__((ext_vector_type(8)));
typedef float    f32x4 __attribute__((ext_vector_type(4)));

__device__ __forceinline__ float ssp(float x) {
    // shifted softplus via fast-math intrinsics: log(1+e^x) - log(2)
    return fmaxf(x, 0.f) + __logf(1.f + __expf(-fabsf(x))) - LOG2F_;
}

// ---------------- filter lookup table: W_i(d) for d = t*DELTA ----------------
__global__ void ftab_kernel(const float* __restrict__ fw1, const float* __restrict__ fb1,
                            const float* __restrict__ fw2, const float* __restrict__ fb2,
                            float* __restrict__ ftab) {
    int t = blockIdx.x;          // 0..ROWS-1
    int i = blockIdx.y;          // interaction 0/1
    int j = threadIdx.x;         // 0..63 channel
    float d = (float)t * DELTA;
    float acc = fb1[i * 64 + j];
    for (int k = 0; k < 51; ++k) {
        float u = d - 0.1f * (float)k;
        float r = __expf(-10.f * u * u);
        acc = fmaf(r, fw1[((size_t)i * 51 + k) * 64 + j], acc);
    }
    __shared__ float h[64];
    h[j] = ssp(acc);
    __syncthreads();
    float o = fb2[i * 64 + j];
    for (int k = 0; k < 64; ++k)
        o = fmaf(h[k], fw2[((size_t)i * 64 + k) * 64 + j], o);
    ftab[((size_t)i * ROWS + t) * 64 + j] = o;
}

// ------- pack lerp endpoints as fp16 pair: 4B/entry, 1MB/interaction --------
__global__ void fpack_kernel(const float* __restrict__ ftab, __half2* __restrict__ fpair) {
    int t = blockIdx.x, i = blockIdx.y, j = threadIdx.x;
    const float* r = ftab + ((size_t)i * ROWS + t) * 64;
    fpair[((size_t)i * TABN + t) * 64 + j] = __floats2half2_rn(r[j], r[j + 64]);
}

// ------- pack/transpose the 7 64x64 node-MLP weights to [n][k] fp16 ---------
__global__ void wpack_kernel(const float* w0, const float* w1, const float* w2,
                             const float* w3, const float* w4, const float* w5,
                             const float* w6, __half* __restrict__ wt) {
    const float* ws[7] = {w0, w1, w2, w3, w4, w5, w6};
    int nrow = blockIdx.x, mat = blockIdx.y, k = threadIdx.x;
    wt[((size_t)mat * 64 + nrow) * 64 + k] = __float2half(ws[mat][k * 64 + nrow]);
}

// ---------------- bucket histogram (LDS-privatized) ----------------
__global__ void bhist_kernel(const int* __restrict__ ei, int* __restrict__ bcnt, int E) {
    __shared__ int h[256];
    int tid = threadIdx.x;
    h[tid] = 0;
    __syncthreads();
    for (int e = blockIdx.x * blockDim.x + tid; e < E; e += gridDim.x * blockDim.x)
        atomicAdd(&h[ei[E + e] >> SBITS], 1);
    __syncthreads();
    if (h[tid]) atomicAdd(&bcnt[tid], h[tid]);
}

// ---------------- bucket exclusive scan (parallel, one block) ----------------
__global__ void bscan_kernel(const int* __restrict__ bcnt, int* __restrict__ bbase,
                             int* __restrict__ bcur, int nbuck) {
    __shared__ int sm[256];
    int tid = threadIdx.x;
    int v = (tid < nbuck) ? bcnt[tid] : 0;
    sm[tid] = v;
    __syncthreads();
    for (int o = 1; o < 256; o <<= 1) {
        int t = (tid >= o) ? sm[tid - o] : 0;
        __syncthreads();
        sm[tid] += t;
        __syncthreads();
    }
    if (tid < nbuck) { bbase[tid] = sm[tid] - v; bcur[tid] = sm[tid] - v; }
    if (tid == 255) bbase[nbuck] = sm[255];
}

// ------- stage: LDS multisplit of edge tiles into bucket-ordered stg ---------
// payload: w0 = src | (t&511)<<17 ; w1 = ti<<20 | frac_q20
__global__ __launch_bounds__(256, 4)
void stage_kernel(const float* __restrict__ pos, const int* __restrict__ ei,
                  int* __restrict__ bcur, int2* __restrict__ stg, int E, int nbuck) {
    __shared__ int hist[256], loff[256], gbase[256], sc[256];
    __shared__ int2 sp[TILE];
    __shared__ short sb[TILE];
    int tid = threadIdx.x;
    int tile0 = blockIdx.x * TILE;
    int cnt = min(TILE, E - tile0);
    hist[tid] = 0;
    __syncthreads();
    int myrank[8], myb[8]; int2 mypay[8];
#pragma unroll
    for (int u = 0; u < 8; ++u) {
        int i = u * 256 + tid;
        myb[u] = -1;
        if (i < cnt) {
            int e = tile0 + i;
            int s = ei[e], t = ei[E + e];
            float dx = pos[3 * s]     - pos[3 * t];
            float dy = pos[3 * s + 1] - pos[3 * t + 1];
            float dz = pos[3 * s + 2] - pos[3 * t + 2];
            float d = sqrtf(dx * dx + dy * dy + dz * dz);
            float ds = fminf(d, DMAX) * INVD;
            int ti = min((int)ds, TABN - 1);
            int frq = min((int)((ds - (float)ti) * 1048576.f), 1048575);
            mypay[u] = make_int2(s | ((t & 511) << 17), (ti << 20) | frq);
            myb[u] = t >> SBITS;
            myrank[u] = atomicAdd(&hist[myb[u]], 1);
        }
    }
    __syncthreads();
    sc[tid] = hist[tid];
    __syncthreads();
    for (int o = 1; o < 256; o <<= 1) {
        int v = (tid >= o) ? sc[tid - o] : 0;
        __syncthreads();
        sc[tid] += v;
        __syncthreads();
    }
    loff[tid] = sc[tid] - hist[tid];
    if (tid < nbuck && hist[tid] > 0) gbase[tid] = atomicAdd(&bcur[tid], hist[tid]);
    __syncthreads();
#pragma unroll
    for (int u = 0; u < 8; ++u)
        if (myb[u] >= 0) {
            int idx = loff[myb[u]] + myrank[u];
            sp[idx] = mypay[u];
            sb[idx] = (short)myb[u];
        }
    __syncthreads();
    for (int i = tid; i < cnt; i += 256) {
        int b = sb[i];
        stg[gbase[b] + (i - loff[b])] = sp[i];
    }
}

// ------- place: per bucket, exact CSR placement with LDS-only atomics --------
__global__ __launch_bounds__(256)
void place_kernel(const int2* __restrict__ stg, const int* __restrict__ bbase,
                  int* __restrict__ off, int2* __restrict__ edata, int n, int nbuck) {
    int b = blockIdx.x;
    int n0 = b << SBITS;
    int nn = min(512, n - n0);
    int q0 = bbase[b], q1 = bbase[b + 1];
    __shared__ int cnt[512], cur[512], sc[256];
    int tid = threadIdx.x;
    cnt[tid] = 0; cnt[tid + 256] = 0;
    __syncthreads();
    for (int q = q0 + tid; q < q1; q += 256)
        atomicAdd(&cnt[(stg[q].x >> 17) & 511], 1);
    __syncthreads();
    int c0 = cnt[2 * tid], c1 = cnt[2 * tid + 1];
    int s = c0 + c1;
    sc[tid] = s;
    __syncthreads();
    for (int o = 1; o < 256; o <<= 1) {
        int v = (tid >= o) ? sc[tid - o] : 0;
        __syncthreads();
        sc[tid] += v;
        __syncthreads();
    }
    int run = sc[tid] - s;        // exclusive over node pairs
    cur[2 * tid] = run;
    cur[2 * tid + 1] = run + c0;
    if (2 * tid < nn)     off[n0 + 2 * tid]     = q0 + run;
    if (2 * tid + 1 < nn) off[n0 + 2 * tid + 1] = q0 + run + c0;
    if (b == nbuck - 1 && tid == 0) off[n] = q1;
    __syncthreads();
    for (int q = q0 + tid; q < q1; q += 256) {
        int2 v = stg[q];
        int p = atomicAdd(&cur[(v.x >> 17) & 511], 1);
        edata[q0 + p] = v;
    }
}

// ---------------- x_h = emb_z[z] (fp16 node rows) ----------------
__global__ void embed_kernel(const int* __restrict__ z, const float* __restrict__ emb,
                             __half* __restrict__ xh, int n) {
    int idx = blockIdx.x * blockDim.x + threadIdx.x;   // over n*8 chunks of 8 ch
    if (idx >= n * 8) return;
    int node = idx >> 3, c = idx & 7;
    const float4* e4 = (const float4*)(emb + (size_t)z[node] * 64 + c * 8);
    float4 a = e4[0], b = e4[1];
    __half2* o2 = (__half2*)(xh + (size_t)node * 64 + c * 8);
    o2[0] = __floats2half2_rn(a.x, a.y);
    o2[1] = __floats2half2_rn(a.z, a.w);
    o2[2] = __floats2half2_rn(b.x, b.y);
    o2[3] = __floats2half2_rn(b.z, b.w);
}

// ---------------- solvent head for the 4 unique solvent rows ----------------
__global__ void solv_kernel(const float* __restrict__ emb_solv,
                            const float* __restrict__ w1, const float* __restrict__ b1,
                            const float* __restrict__ w2, const float* __restrict__ b2,
                            float* __restrict__ s4) {
    __shared__ float h[4][64];
    int t = threadIdx.x, r = t >> 6, j = t & 63;
    float acc = b1[j];
    for (int k = 0; k < 64; ++k) acc = fmaf(emb_solv[r * 64 + k], w1[k * 64 + j], acc);
    h[r][j] = ssp(acc);
    __syncthreads();
    if (j < 32) {
        float a = b2[j];
        for (int k = 0; k < 64; ++k) a = fmaf(h[r][k], w2[k * 32 + j], a);
        s4[r * 32 + j] = a;
    }
}

// ------------- m0 = emb_z[z]@W+b, fp16 out; reads L1-resident emb table -----
__global__ __launch_bounds__(256, 4)
void mm1h_kernel(const int* __restrict__ z, const float* __restrict__ emb,
                 const float* __restrict__ w, const float* __restrict__ b,
                 __half* __restrict__ out, int n) {
    int tid = threadIdx.x;
    int q = __builtin_amdgcn_readfirstlane(tid >> 6);   // 0..3, wave-uniform
    int node = blockIdx.x * 64 + (tid & 63);
    node = min(node, n - 1);                    // no divergent return
    int zi = z[node];
    const float4* in4 = (const float4*)(emb + (size_t)zi * 64);  // 25KB table: L1 hit
    const float* wq = w + q * 16;
    const float* bq = b + q * 16;
    float acc[16];
#pragma unroll
    for (int j = 0; j < 16; ++j) acc[j] = bq[j];
#pragma unroll 2
    for (int kk = 0; kk < 16; ++kk) {
        float4 xv = in4[kk];
        const float* w0 = wq + kk * 256;
#pragma unroll
        for (int j = 0; j < 16; ++j) acc[j] = fmaf(xv.x, w0[j],       acc[j]);
#pragma unroll
        for (int j = 0; j < 16; ++j) acc[j] = fmaf(xv.y, w0[64 + j],  acc[j]);
#pragma unroll
        for (int j = 0; j < 16; ++j) acc[j] = fmaf(xv.z, w0[128 + j], acc[j]);
#pragma unroll
        for (int j = 0; j < 16; ++j) acc[j] = fmaf(xv.w, w0[192 + j], acc[j]);
    }
    __half2* o2 = (__half2*)(out + (size_t)node * 64 + q * 16);
#pragma unroll
    for (int c = 0; c < 8; ++c)
        o2[c] = __floats2half2_rn(acc[2 * c], acc[2 * c + 1]);
}

// ---------------- per-node aggregation: agg[t] = sum_e m[src]*W(d) ----------
__global__ void agg_kernel(const int* __restrict__ off, const int2* __restrict__ edata,
                           const __half* __restrict__ m, const __half2* __restrict__ fpair,
                           __half* __restrict__ agg, int n) {
    int wave = (blockIdx.x * blockDim.x + threadIdx.x) >> 6;
    int lane = threadIdx.x & 63;
    if (wave >= n) return;
    int e0 = __builtin_amdgcn_readfirstlane(off[wave]);
    int e1 = __builtin_amdgcn_readfirstlane(off[wave + 1]);
    const float FRS = 1.f / 1048576.f;
    float acc[4] = {0.f, 0.f, 0.f, 0.f};
    int e = e0;
    for (; e + 8 <= e1; e += 8) {
        float mv[8], wv[8];
#pragma unroll
        for (int u = 0; u < 8; ++u) {
            int2 pd = edata[e + u];
            int px = __builtin_amdgcn_readfirstlane(pd.x);
            int py = __builtin_amdgcn_readfirstlane(pd.y);
            int s = px & 0x1FFFF;
            unsigned ti = ((unsigned)py) >> 20;
            float fr = (float)(py & 0xFFFFF) * FRS;
            mv[u] = __half2float(m[(size_t)s * 64 + lane]);
            float2 wf = __half22float2(fpair[(size_t)ti * 64 + lane]);
            wv[u] = fmaf(fr, wf.y - wf.x, wf.x);
        }
#pragma unroll
        for (int u = 0; u < 8; ++u) acc[u & 3] = fmaf(mv[u], wv[u], acc[u & 3]);
    }
    for (; e + 4 <= e1; e += 4) {
        float mv[4], wv[4];
#pragma unroll
        for (int u = 0; u < 4; ++u) {
            int2 pd = edata[e + u];
            int px = __builtin_amdgcn_readfirstlane(pd.x);
            int py = __builtin_amdgcn_readfirstlane(pd.y);
            int s = px & 0x1FFFF;
            unsigned ti = ((unsigned)py) >> 20;
            float fr = (float)(py & 0xFFFFF) * FRS;
            mv[u] = __half2float(m[(size_t)s * 64 + lane]);
            float2 wf = __half22float2(fpair[(size_t)ti * 64 + lane]);
            wv[u] = fmaf(fr, wf.y - wf.x, wf.x);
        }
#pragma unroll
        for (int u = 0; u < 4; ++u) acc[u] = fmaf(mv[u], wv[u], acc[u]);
    }
    for (; e < e1; ++e) {
        int2 pd = edata[e];
        int px = __builtin_amdgcn_readfirstlane(pd.x);
        int py = __builtin_amdgcn_readfirstlane(pd.y);
        int s = px & 0x1FFFF;
        unsigned ti = ((unsigned)py) >> 20;
        float fr = (float)(py & 0xFFFFF) * FRS;
        float mm = __half2float(m[(size_t)s * 64 + lane]);
        float2 wf = __half22float2(fpair[(size_t)ti * 64 + lane]);
        acc[0] = fmaf(mm, fmaf(fr, wf.y - wf.x, wf.x), acc[0]);
    }
    agg[(size_t)wave * 64 + lane] = __float2half((acc[0] + acc[1]) + (acc[2] + acc[3]));
}

// ===== MFMA 2-layer node MLP: out = ssp(in@W1+b1)@W2+b2 (+res) (+next m) =====
// 4 waves/block, 16-node tile per wave, mfma_f32_16x16x32_f16.
// Fragment layouts: A row = lane&15, k = 8*(lane>>4)+i (contiguous 16B);
// B col = lane&15, same k split (weights pre-transposed [n][k] fp16);
// C/D col = lane&15, row = (lane>>4)*4 + reg  [HW-verified, guide §3].
// h routed through wave-private padded LDS (row stride 72 halves -> 2-way max
// bank aliasing); no barriers needed (same-wave LDS ordered by waitcnt).
template <bool RES, bool EMIT_M>
__global__ __launch_bounds__(256, 4)
void mfmlp_kernel(const __half* __restrict__ in,
                  const __half* __restrict__ w1t, const float* __restrict__ b1,
                  const __half* __restrict__ w2t, const float* __restrict__ b2,
                  const __half* __restrict__ res, __half* __restrict__ out,
                  const __half* __restrict__ lwt, const float* __restrict__ lb,
                  __half* __restrict__ mout, int n) {
    __shared__ __half hls[4][16][72];
    int tid = threadIdx.x;
    int w = tid >> 6, l = tid & 63;
    int lm = l & 15, lg = l >> 4;
    int base = blockIdx.x * 64 + w * 16;
    int arow = min(base + lm, n - 1);

    // ---- layer 1: acc[nt] = in-tile @ W1[:, nt*16..] ----
    f32x4 acc[4];
#pragma unroll
    for (int nt = 0; nt < 4; ++nt) acc[nt] = (f32x4){0.f, 0.f, 0.f, 0.f};
#pragma unroll
    for (int s = 0; s < 2; ++s) {
        f16x8 a = *(const f16x8*)(in + (size_t)arow * 64 + 32 * s + 8 * lg);
#pragma unroll
        for (int nt = 0; nt < 4; ++nt) {
            f16x8 b = *(const f16x8*)(w1t + (size_t)(lm + 16 * nt) * 64 + 32 * s + 8 * lg);
            acc[nt] = __builtin_amdgcn_mfma_f32_16x16x32_f16(a, b, acc[nt], 0, 0, 0);
        }
    }
#pragma unroll
    for (int nt = 0; nt < 4; ++nt) {
        float bb = b1[lm + 16 * nt];
#pragma unroll
        for (int i = 0; i < 4; ++i)
            hls[w][lg * 4 + i][lm + 16 * nt] = __float2half(ssp(acc[nt][i] + bb));
    }

    // ---- layer 2: acc2[nt] = h-tile @ W2[:, nt*16..] ----
    f32x4 acc2[4];
#pragma unroll
    for (int nt = 0; nt < 4; ++nt) acc2[nt] = (f32x4){0.f, 0.f, 0.f, 0.f};
#pragma unroll
    for (int s = 0; s < 2; ++s) {
        f16x8 a = *(const f16x8*)(&hls[w][lm][32 * s + 8 * lg]);
#pragma unroll
        for (int nt = 0; nt < 4; ++nt) {
            f16x8 b = *(const f16x8*)(w2t + (size_t)(lm + 16 * nt) * 64 + 32 * s + 8 * lg);
            acc2[nt] = __builtin_amdgcn_mfma_f32_16x16x32_f16(a, b, acc2[nt], 0, 0, 0);
        }
    }
    // bias + residual + store (predicated: padded rows never written)
#pragma unroll
    for (int nt = 0; nt < 4; ++nt) {
        float bb = b2[lm + 16 * nt];
#pragma unroll
        for (int i = 0; i < 4; ++i) {
            int r = base + lg * 4 + i;
            if (r < n) {
                float v = acc2[nt][i] + bb;
                if constexpr (RES) v += __half2float(res[(size_t)r * 64 + lm + 16 * nt]);
                out[(size_t)r * 64 + lm + 16 * nt] = __float2half(v);
                if constexpr (EMIT_M) hls[w][lg * 4 + i][lm + 16 * nt] = __float2half(v);
            }
        }
    }
    if constexpr (EMIT_M) {
        // ---- layer 3: next m = out-tile @ LW ----
        f32x4 acc3[4];
#pragma unroll
        for (int nt = 0; nt < 4; ++nt) acc3[nt] = (f32x4){0.f, 0.f, 0.f, 0.f};
#pragma unroll
        for (int s = 0; s < 2; ++s) {
            f16x8 a = *(const f16x8*)(&hls[w][lm][32 * s + 8 * lg]);
#pragma unroll
            for (int nt = 0; nt < 4; ++nt) {
                f16x8 b = *(const f16x8*)(lwt + (size_t)(lm + 16 * nt) * 64 + 32 * s + 8 * lg);
                acc3[nt] = __builtin_amdgcn_mfma_f32_16x16x32_f16(a, b, acc3[nt], 0, 0, 0);
            }
        }
#pragma unroll
        for (int nt = 0; nt < 4; ++nt) {
            float bb = lb[lm + 16 * nt];
#pragma unroll
            for (int i = 0; i < 4; ++i) {
                int r = base + lg * 4 + i;
                if (r < n)
                    mout[(size_t)r * 64 + lm + 16 * nt] = __float2half(acc3[nt][i] + bb);
            }
        }
    }
}

// ---------------- scatter-mean pooling (fp16 input, batch sorted) -----------
__global__ void pool_kernel(const __half* __restrict__ h, const int* __restrict__ batch,
                            float* __restrict__ pooled, int n_nodes) {
    int g = blockIdx.x, j = threadIdx.x;   // block = 64
    int lo = 0, hi = n_nodes;
    while (lo < hi) { int mid = (lo + hi) >> 1; if (batch[mid] < g) lo = mid + 1; else hi = mid; }
    int start = lo;
    int lo2 = start, hi2 = n_nodes;
    while (lo2 < hi2) { int mid = (lo2 + hi2) >> 1; if (batch[mid] < g + 1) lo2 = mid + 1; else hi2 = mid; }
    int end = lo2;
    float acc = 0.f;
    for (int r = start; r < end; ++r) acc += __half2float(h[(size_t)r * 64 + j]);
    float cnt = (float)(end - start);
    pooled[(size_t)g * 64 + j] = acc / fmaxf(cnt, 1.f);
}

// ---------------- final graph head: 96 -> 128 -> 32 -> 1 --------------------
__global__ void post2_kernel(const float* __restrict__ pooled, const float* __restrict__ s4,
                             const int* __restrict__ solvent,
                             const float* __restrict__ w1, const float* __restrict__ b1,
                             const float* __restrict__ w2, const float* __restrict__ b2,
                             const float* __restrict__ w3, const float* __restrict__ b3,
                             float* __restrict__ out) {
    __shared__ float in96[96];
    __shared__ float l1[128];
    __shared__ float l2[32];
    int g = blockIdx.x, t = threadIdx.x;   // block = 128
    if (t < 64)      in96[t] = pooled[(size_t)g * 64 + t];
    else if (t < 96) in96[t] = s4[solvent[g] * 32 + (t - 64)];
    __syncthreads();
    float acc = b1[t];
    for (int k = 0; k < 96; ++k) acc = fmaf(in96[k], w1[k * 128 + t], acc);
    l1[t] = ssp(acc);
    __syncthreads();
    if (t < 32) {
        float a = b2[t];
        for (int k = 0; k < 128; ++k) a = fmaf(l1[k], w2[k * 32 + t], a);
        l2[t] = ssp(a);
    }
    __syncthreads();
    if (t < 32) {
        float p = l2[t] * w3[t];
        for (int o = 16; o >= 1; o >>= 1) p += __shfl_down(p, o);
        if (t == 0) out[g] = p + b3[0];
    }
}

extern "C" void kernel_launch(void* const* d_in, const int* in_sizes, int n_in,
                              void* d_out, int out_size, void* d_ws, size_t ws_size,
                              hipStream_t stream) {
    const float* pos      = (const float*)d_in[0];
    const int*   ei       = (const int*)d_in[1];
    const int*   z        = (const int*)d_in[2];
    const int*   batch    = (const int*)d_in[3];
    const int*   solvent  = (const int*)d_in[4];
    const float* emb_z    = (const float*)d_in[5];
    const float* emb_solv = (const float*)d_in[6];
    const float* solv_w1  = (const float*)d_in[7];  const float* solv_b1 = (const float*)d_in[8];
    const float* solv_w2  = (const float*)d_in[9];  const float* solv_b2 = (const float*)d_in[10];
    const float* lin1_w   = (const float*)d_in[11]; const float* lin1_b  = (const float*)d_in[12];
    const float* mlp_w1   = (const float*)d_in[13]; const float* mlp_b1  = (const float*)d_in[14];
    const float* mlp_w2   = (const float*)d_in[15]; const float* mlp_b2  = (const float*)d_in[16];
    const float* filt_w1  = (const float*)d_in[17]; const float* filt_b1 = (const float*)d_in[18];
    const float* filt_w2  = (const float*)d_in[19]; const float* filt_b2 = (const float*)d_in[20];
    const float* post_w1  = (const float*)d_in[21]; const float* post_b1 = (const float*)d_in[22];
    const float* post_w2  = (const float*)d_in[23]; const float* post_b2 = (const float*)d_in[24];
    const float* p2w1 = (const float*)d_in[25]; const float* p2b1 = (const float*)d_in[26];
    const float* p2w2 = (const float*)d_in[27]; const float* p2b2 = (const float*)d_in[28];
    const float* p2w3 = (const float*)d_in[29]; const float* p2b3 = (const float*)d_in[30];
    float* out = (float*)d_out;

    const int N = in_sizes[2];
    const int E = in_sizes[1] / 2;
    const int G = in_sizes[4];
    const int NBUCK = (N + (1 << SBITS) - 1) >> SBITS;

    char* wp = (char*)d_ws;
    auto alloc = [&](size_t bytes) -> void* {
        void* r = (void*)wp;
        wp += (bytes + 255) & ~(size_t)255;
        return r;
    };
    int2*    stg    = (int2*)   alloc((size_t)E * 8);
    int2*    edata  = (int2*)   alloc((size_t)E * 8);
    int*     bcnt   = (int*)    alloc(256 * 4);
    int*     bbase  = (int*)    alloc(257 * 4);
    int*     bcur   = (int*)    alloc(256 * 4);
    int*     off    = (int*)    alloc((size_t)(N + 1) * 4);
    float*   ftab   = (float*)  alloc((size_t)2 * ROWS * 64 * 4);
    __half2* fpair  = (__half2*)alloc((size_t)2 * TABN * 64 * 4);
    __half*  wt     = (__half*) alloc((size_t)7 * 4096 * 2);
    float*   s4     = (float*)  alloc(4 * 32 * 4);
    __half*  x_h    = (__half*) alloc((size_t)N * 64 * 2);
    __half*  m_h    = (__half*) alloc((size_t)N * 64 * 2);
    __half*  m_h2   = (__half*) alloc((size_t)N * 64 * 2);
    __half*  agg_h  = (__half*) alloc((size_t)N * 64 * 2);
    __half*  hbuf   = (__half*) alloc((size_t)N * 64 * 2);
    float*   pooled = (float*)  alloc((size_t)G * 64 * 4);
    (void)ws_size; (void)n_in; (void)out_size;

    hipMemsetAsync(bcnt, 0, 256 * 4, stream);

    ftab_kernel<<<dim3(ROWS, 2), 64, 0, stream>>>(filt_w1, filt_b1, filt_w2, filt_b2, ftab);
    fpack_kernel<<<dim3(TABN, 2), 64, 0, stream>>>(ftab, fpair);
    // wt: 0=mlp_w1[0] 1=mlp_w2[0] 2=mlp_w1[1] 3=mlp_w2[1] 4=post_w1 5=post_w2 6=lin1_w[1]
    wpack_kernel<<<dim3(64, 7), 64, 0, stream>>>(mlp_w1, mlp_w2, mlp_w1 + 4096,
                                                 mlp_w2 + 4096, post_w1, post_w2,
                                                 lin1_w + 4096, wt);
    bhist_kernel<<<512, 256, 0, stream>>>(ei, bcnt, E);
    bscan_kernel<<<1, 256, 0, stream>>>(bcnt, bbase, bcur, NBUCK);
    stage_kernel<<<(E + TILE - 1) / TILE, 256, 0, stream>>>(pos, ei, bcur, stg, E, NBUCK);
    place_kernel<<<NBUCK, 256, 0, stream>>>(stg, bbase, off, edata, N, NBUCK);
    embed_kernel<<<((size_t)N * 8 + 255) / 256, 256, 0, stream>>>(z, emb_z, x_h, N);
    solv_kernel<<<1, 256, 0, stream>>>(emb_solv, solv_w1, solv_b1, solv_w2, solv_b2, s4);

    int mmg = (N + 63) / 64;
    // interaction 0: m0 = emb_z[z] @ lin1[0]
    mm1h_kernel<<<mmg, 256, 0, stream>>>(z, emb_z, lin1_w, lin1_b, m_h, N);
    agg_kernel<<<(N + 3) / 4, 256, 0, stream>>>(off, edata, m_h, fpair, agg_h, N);
    // MFMA MLP + residual -> x_h, emit m1 = x_h @ lin1[1]
    mfmlp_kernel<true, true><<<mmg, 256, 0, stream>>>(
        agg_h, wt, mlp_b1, wt + 4096, mlp_b2, x_h, x_h,
        wt + 6 * 4096, lin1_b + 64, m_h2, N);
    // interaction 1
    agg_kernel<<<(N + 3) / 4, 256, 0, stream>>>(off, edata, m_h2,
                                                fpair + (size_t)TABN * 64, agg_h, N);
    mfmlp_kernel<true, false><<<mmg, 256, 0, stream>>>(
        agg_h, wt + 2 * 4096, mlp_b1 + 64, wt + 3 * 4096, mlp_b2 + 64, x_h, x_h,
        nullptr, nullptr, nullptr, N);
    // post MLP: hbuf = ssp(x@pw1+b1)@pw2+b2 (fp16, feeds pool only)
    mfmlp_kernel<false, false><<<mmg, 256, 0, stream>>>(
        x_h, wt + 4 * 4096, post_b1, wt + 5 * 4096, post_b2, nullptr, hbuf,
        nullptr, nullptr, nullptr, N);

    pool_kernel<<<G, 64, 0, stream>>>(hbuf, batch, pooled, N);
    post2_kernel<<<G, 128, 0, stream>>>(pooled, s4, solvent, p2w1, p2b1, p2w2, p2b2,
                                        p2w3, p2b3, out);
}